// Round 13
// baseline (327.101 us; speedup 1.0000x reference)
//
#include <hip/hip_runtime.h>
#include <hip/hip_bf16.h>

#define N      4096
#define NFEAT  512
#define NHID   64
#define NHEADS 8
#define NCLASS 40
#define ALPHA  0.2f
#define LOG2E  1.44269504f

typedef unsigned short u16;
typedef unsigned int   u32;
typedef __attribute__((ext_vector_type(8))) short bf16x8;
typedef __attribute__((ext_vector_type(4))) float f32x4;

// bf16 bits -> f32
__device__ __forceinline__ float b2f(u16 u) {
    return __uint_as_float(((u32)u) << 16);
}
// RNE-rounded value kept in HIGH 16 bits
__device__ __forceinline__ u32 rnd_hi(float f) {
    u32 u = __float_as_uint(f);
    return u + 0x7FFFu + ((u >> 16) & 1u);
}
// pack two f32 -> two bf16 (lo in low 16) via HW v_cvt_pk_bf16_f32 (gfx950)
__device__ __forceinline__ u32 pk2(float lo, float hi) {
    __hip_bfloat162 h = __float22bfloat162_rn(make_float2(lo, hi));
    return *(u32*)&h;
}
// single f32 -> bf16 bits (RNE)
__device__ __forceinline__ u16 f2b(float f) {
    return (u16)(rnd_hi(f) >> 16);
}
// masked exp2 of leaky-relu in log2 domain: raw v_exp_f32, no OCML guards
__device__ __forceinline__ float mexp(int m, float t) {
    return m ? __builtin_amdgcn_exp2f(fmaxf(t, ALPHA * t)) : 0.f;
}
// constant all-ones bf16 B-fragment (every output column = row sum)
__device__ __forceinline__ bf16x8 ones_frag() {
    union { u16 u[8]; bf16x8 v; } o;
    #pragma unroll
    for (int j = 0; j < 8; ++j) o.u[j] = 0x3F80;
    return o.v;
}
// async global->LDS DMA, 16B per lane; LDS dest = wave-uniform base + lane*16.
// Completion is guaranteed by the vmcnt(0) drain inside __syncthreads().
__device__ __forceinline__ void gload_lds16(const u16* g, u16* l) {
    __builtin_amdgcn_global_load_lds(
        (const __attribute__((address_space(1))) void*)g,
        (__attribute__((address_space(3))) void*)l,
        16, 0, 0);
}

// ---------------- KCX: x f32 -> xb bf16 (same layout) ---------------------------
__global__ __launch_bounds__(256) void kcx(const float* __restrict__ x,
                                           u16* __restrict__ xb) {
    const int g = blockIdx.x * 256 + threadIdx.x;       // 262144 threads x 8 elems
    const size_t base = (size_t)g * 8;
    float4 v0 = *(const float4*)&x[base];
    float4 v1 = *(const float4*)&x[base + 4];
    uint4 o;
    o.x = pk2(v0.x, v0.y); o.y = pk2(v0.z, v0.w);
    o.z = pk2(v1.x, v1.y); o.w = pk2(v1.z, v1.w);
    *(uint4*)&xb[base] = o;
}

// ---------------- KCW: W1 [h][f][d] f32 -> W1b bf16 [h][d][f] -------------------
__global__ __launch_bounds__(256) void kcw(const float* __restrict__ W1,
                                           u16* __restrict__ W1b) {
    __shared__ float ts[64 * 68];   // [f-local][d], pitch 68
    const int t  = threadIdx.x;
    const int f0 = blockIdx.x * 64;
    const int h  = blockIdx.y;
    #pragma unroll
    for (int i = 0; i < 4; ++i) {
        int flat = t + 256 * i;
        int row = flat >> 4;                    // f-local
        int c4  = (flat & 15) * 4;              // d
        *(float4*)&ts[row * 68 + c4] =
            *(const float4*)&W1[((size_t)h * 512 + f0 + row) * 64 + c4];
    }
    __syncthreads();
    const int d  = t >> 2;
    const int fs = (t & 3) * 16;
    u32 p[8];
    #pragma unroll
    for (int j = 0; j < 8; ++j)
        p[j] = pk2(ts[(fs + 2 * j) * 68 + d], ts[(fs + 2 * j + 1) * 68 + d]);
    u32* dst = (u32*)&W1b[((size_t)(h * 64 + d)) * 512 + f0 + fs];
    *(uint4*)dst       = make_uint4(p[0], p[1], p[2], p[3]);
    *(uint4*)(dst + 4) = make_uint4(p[4], p[5], p[6], p[7]);
}

// ---------------- K1M: Wh1T bf16 + fused F1/F2 epilogue -------------------------
// Round-7 proven version: gl_lds DMA double-buffered staging, XOR swizzle,
// one barrier per K-step. LDS 32 KB. grid (64 n-tiles, 8 heads) x 256.
__global__ __launch_bounds__(256, 4) void k1m_gemm1(const u16* __restrict__ xb,
                                                    const u16* __restrict__ W1b,
                                                    const float* __restrict__ a1,
                                                    u16* __restrict__ Wh1T,
                                                    float* __restrict__ F1,
                                                    float* __restrict__ F2) {
    __shared__ __align__(16) u16 xs[2][64 * 64];    // [n-local][f-chunk]
    __shared__ __align__(16) u16 wvs[2][64 * 64];   // [d][f-chunk]
    const int t    = threadIdx.x;
    const int n0   = blockIdx.x * 64;
    const int h    = blockIdx.y;
    const int lane = t & 63;
    const int l15  = lane & 15;
    const int q    = lane >> 4;
    const int wv   = t >> 6;
    const int wrow = wv * 16;
    const int lsub = lane >> 3;        // row-sub 0..7
    const int slot = lane & 7;         // 16B col slot 0..7
    const int xb7  = l15 & 7;          // read-side swizzle key

    // DMA sources, pre-swizzled: LDS[r][slot] = G[r][slot ^ (r&7)]; r&7 == lsub
    const u16* gx[2];
    const u16* gw[2];
    #pragma unroll
    for (int i = 0; i < 2; ++i) {
        const int r  = wv * 16 + i * 8 + lsub;
        const int sc = (slot ^ lsub) * 8;
        gx[i] = xb  + (size_t)(n0 + r) * 512 + sc;
        gw[i] = W1b + ((size_t)(h * 64 + r)) * 512 + sc;
    }

    f32x4 acc[4];
    #pragma unroll
    for (int df = 0; df < 4; ++df)
        #pragma unroll
        for (int r = 0; r < 4; ++r) acc[df][r] = 0.f;

#define K1_DMA(P, F0)                                                          \
    {                                                                          \
        _Pragma("unroll")                                                      \
        for (int i = 0; i < 2; ++i) {                                          \
            gload_lds16(gx[i] + (F0), &xs[P][(wv * 16 + i * 8) * 64]);         \
            gload_lds16(gw[i] + (F0), &wvs[P][(wv * 16 + i * 8) * 64]);        \
        }                                                                      \
    }
#define K1_MFMA(P)                                                            \
    {                                                                          \
        _Pragma("unroll")                                                      \
        for (int ks = 0; ks < 2; ++ks) {                                       \
            const int sl = ((ks * 4 + q) ^ xb7) * 8;                           \
            bf16x8 a = *(const bf16x8*)&xs[P][(wrow + l15) * 64 + sl];         \
            _Pragma("unroll")                                                  \
            for (int df = 0; df < 4; ++df) {                                   \
                bf16x8 b = *(const bf16x8*)&wvs[P][(df * 16 + l15) * 64 + sl]; \
                acc[df] = __builtin_amdgcn_mfma_f32_16x16x32_bf16(a, b, acc[df], 0, 0, 0); \
            }                                                                  \
        }                                                                      \
    }

    K1_DMA(0, 0)
    __syncthreads();
    for (int f0 = 0; f0 < 512; f0 += 128) {
        K1_DMA(1, f0 + 64)          // covered by MFMA(0) + other waves
        K1_MFMA(0)
        __syncthreads();            // drains DMA -> buf1 ready
        if (f0 + 128 < 512)
            K1_DMA(0, f0 + 128)
        K1_MFMA(1)
        __syncthreads();
    }
#undef K1_DMA
#undef K1_MFMA

    // Wh1T store: C row = q*4+r (n-local), col = l15 (d-local)
    #pragma unroll
    for (int df = 0; df < 4; ++df) {
        uint2 o;
        o.x = pk2(acc[df][0], acc[df][1]);
        o.y = pk2(acc[df][2], acc[df][3]);
        *(uint2*)&Wh1T[((size_t)(h * 64 + df * 16 + l15)) * 4096 + n0 + wrow + q * 4] = o;
    }
    // fused F1/F2: f = sum_d Wh[n][h*64+d] * a1[h,{0,1},d], reduce over l15 group
    float a1v[4], a2v[4];
    #pragma unroll
    for (int df = 0; df < 4; ++df) {
        a1v[df] = a1[h * 128 + df * 16 + l15];
        a2v[df] = a1[h * 128 + 64 + df * 16 + l15];
    }
    #pragma unroll
    for (int r = 0; r < 4; ++r) {
        float s1 = 0.f, s2 = 0.f;
        #pragma unroll
        for (int df = 0; df < 4; ++df) {
            s1 += acc[df][r] * a1v[df];
            s2 += acc[df][r] * a2v[df];
        }
        #pragma unroll
        for (int off = 8; off >= 1; off >>= 1) {
            s1 += __shfl_xor(s1, off);
            s2 += __shfl_xor(s2, off);
        }
        if (l15 == 0) {
            int n = n0 + wrow + q * 4 + r;
            F1[h * 4096 + n] = s1 * LOG2E;
            F2[h * 4096 + n] = s2 * LOG2E;
        }
    }
}

// ---------------- K3: layer-1 attention, fused, 32-row tiles, BK=256 ------------
// Round-7 skeleton with the m-tile doubled to 256 cols: 16 iterations x 2
// barriers = 32 barriers/block (was 64) — isolates barrier-count cost.
// Same gl_lds+XOR-swizzle whT staging (slot index now 5 bits; XOR key still
// low 3 bits on both sides), same consume-then-issue adj/F2 prefetch (8 int4),
// same K-accumulation order (bitwise-identical output).
// LDS 49.3 KB -> 3 blocks/CU. grid (128 n-tiles, 8 heads) x 256.
__global__ __launch_bounds__(256, 3) void k3_attn1(const int* __restrict__ adj1,
                                                   const u16* __restrict__ Wh1T,
                                                   const float* __restrict__ F1,
                                                   const float* __restrict__ F2,
                                                   float* __restrict__ h1) {
    __shared__ __align__(16) u16 wbf[32 * 264];   // A-tile, pitch 264
    __shared__ __align__(16) u16 whT[64 * 256];   // B-tile, linear+swizzled
    __shared__ float f1s[32];
    __shared__ float zs[32];
    const int t     = threadIdx.x;
    const int n0    = blockIdx.x * 32;
    const int h     = blockIdx.y;
    const int lane  = t & 63;
    const int l15   = lane & 15;
    const int q     = lane >> 4;
    const int wv    = t >> 6;
    const int rb    = (wv & 1) * 16;          // row-block base
    const int dh    = wv >> 1;                // df-half: computes df = dh*2+j
    const int c4    = (t & 31) * 4;           // mask-gen: 4 consecutive cols
    const int rg    = t >> 5;                 // mask-gen: row group 0..7
    const bf16x8 bones = ones_frag();
    if (t < 32) f1s[t] = F1[h * N + n0 + t];

    // gl_lds staging map: wave wv, inst i (0..7) covers rows wv*16 + i*2 +
    // (lane>>5); 32 16B-slots per 512B row; source pre-swizzled on the low
    // 3 slot bits: G[r][slot ^ (r&7)]
    const u16* gsrc[8];
    #pragma unroll
    for (int i = 0; i < 8; ++i) {
        const int row_l = wv * 16 + i * 2 + (lane >> 5);
        const int sc    = (((lane & 31) ^ (row_l & 7))) * 8;
        gsrc[i] = Wh1T + ((size_t)(h * 64 + row_l)) * 4096 + sc;
    }
    const int xb7 = l15 & 7;                  // read-side swizzle key

    f32x4 accd[2], accz;
    #pragma unroll
    for (int j = 0; j < 2; ++j)
        #pragma unroll
        for (int r = 0; r < 4; ++r) accd[j][r] = 0.f;
    #pragma unroll
    for (int r = 0; r < 4; ++r) accz[r] = 0.f;

    // initial prefetch: iter-0 adj tile (8 int4: rows rg+8*(i&3), col half i>>2)
    // + both F2 vectors
    int4 aprev[8];
    #pragma unroll
    for (int i = 0; i < 8; ++i)
        aprev[i] = *(const int4*)
            &adj1[(size_t)(n0 + rg + 8 * (i & 3)) * N + c4 + 128 * (i >> 2)];
    float4 f2n0 = *(const float4*)&F2[h * N + c4];
    float4 f2n1 = *(const float4*)&F2[h * N + c4 + 128];
    __syncthreads();

    for (int m0 = 0; m0 < 4096; m0 += 256) {
        // ---- issue whT DMA for this tile (covered by mask-gen VALU) ----
        #pragma unroll
        for (int i = 0; i < 8; ++i)
            gload_lds16(gsrc[i] + m0, &whT[(wv * 16 + i * 2) * 256]);
        // ---- mask-gen; consume aprev[i], immediately issue its replacement ----
        const float4 P0 = f2n0;
        const float4 P1 = f2n1;
        const int mn = (m0 + 256 < 4096) ? m0 + 256 : 0;   // wrap harmless
        f2n0 = *(const float4*)&F2[h * N + mn + c4];
        f2n1 = *(const float4*)&F2[h * N + mn + c4 + 128];
        #pragma unroll
        for (int i = 0; i < 8; ++i) {
            const int rr = rg + 8 * (i & 3);
            const int cb = c4 + 128 * (i >> 2);
            int4 a4 = aprev[i];
            aprev[i] = *(const int4*)&adj1[(size_t)(n0 + rr) * N + mn + cb];
            const float4 Pv = (i >> 2) ? P1 : P0;
            float f1v = f1s[rr];
            float w0 = mexp(a4.x, f1v + Pv.x);
            float w1 = mexp(a4.y, f1v + Pv.y);
            float w2 = mexp(a4.z, f1v + Pv.z);
            float w3 = mexp(a4.w, f1v + Pv.w);
            uint2 pk;
            pk.x = pk2(w0, w1);
            pk.y = pk2(w2, w3);
            *(uint2*)&wbf[rr * 264 + cb] = pk;
        }
        __syncthreads();   // vmcnt(0) drain: DMA + prefetches already covered
        // ---- compute: 8 K-steps x (2 data frags + ones frag on dh==0) ----
        #pragma unroll
        for (int ks = 0; ks < 8; ++ks) {
            int k0 = ks * 32 + q * 8;
            bf16x8 a = *(const bf16x8*)&wbf[(rb + l15) * 264 + k0];
            #pragma unroll
            for (int j = 0; j < 2; ++j) {
                const int df = dh * 2 + j;
                bf16x8 b = *(const bf16x8*)
                    &whT[(df * 16 + l15) * 256 + (((ks * 4 + q) ^ xb7) * 8)];
                accd[j] = __builtin_amdgcn_mfma_f32_16x16x32_bf16(a, b, accd[j], 0, 0, 0);
            }
            if (dh == 0)
                accz = __builtin_amdgcn_mfma_f32_16x16x32_bf16(a, bones, accz, 0, 0, 0);
        }
        __syncthreads();
    }
    // denominator broadcast across the df-split, then normalize + ELU -> h1
    if (dh == 0 && l15 == 0) {
        #pragma unroll
        for (int r = 0; r < 4; ++r) zs[rb + q * 4 + r] = accz[r];
    }
    __syncthreads();
    #pragma unroll
    for (int r = 0; r < 4; ++r) {
        const int nl = rb + q * 4 + r;
        const float z = fmaxf(zs[nl], 1e-30f);
        #pragma unroll
        for (int j = 0; j < 2; ++j) {
            float v = accd[j][r] / z;
            v = v > 0.f ? v : __expf(v) - 1.f;
            h1[(size_t)(n0 + nl) * 512 + h * 64 + (dh * 2 + j) * 16 + l15] = v;
        }
    }
}

// ---------------- K4: fused Wh2 GEMM + F1o/F2o + Wh2T bf16 ----------------------
// wave = one n (lane = c); grid 1024 x 256.
__global__ __launch_bounds__(256) void k4_gemm2(const float* __restrict__ h1,
                                                const float* __restrict__ Wo,
                                                const float* __restrict__ ao,
                                                float* __restrict__ F1o,
                                                float* __restrict__ F2o,
                                                u16* __restrict__ Wh2T) {
    const int t = threadIdx.x;
    const int c = t & 63;
    const int n = blockIdx.x * 4 + (t >> 6);
    float acc = 0.f;
    if (c < NCLASS) {
        const float* hrow = &h1[(size_t)n * 512];
        #pragma unroll 8
        for (int f = 0; f < 512; ++f)
            acc += hrow[f] * Wo[f * NCLASS + c];
        Wh2T[(size_t)c * 4096 + n] = f2b(acc);
    }
    float s1 = (c < NCLASS) ? acc * ao[c] : 0.f;
    float s2 = (c < NCLASS) ? acc * ao[NCLASS + c] : 0.f;
    #pragma unroll
    for (int off = 32; off >= 1; off >>= 1) {
        s1 += __shfl_xor(s1, off);
        s2 += __shfl_xor(s2, off);
    }
    if (c == 0) {
        F1o[n] = s1 * LOG2E;
        F2o[n] = s2 * LOG2E;
    }
}

// ---------------- K5a: layer-2 attention partials via MFMA ----------------------
// Round-5/7 proven version (gl_lds/swizzle staging, post-mask-gen prefetch,
// 5 waves/EU). LDS 29.9 KB. grid (64, 16) x 256.
__global__ __launch_bounds__(256, 5) void k5a_attn2(const int* __restrict__ adj0,
                                                    const u16* __restrict__ Wh2T,
                                                    const float* __restrict__ F1o,
                                                    const float* __restrict__ F2o,
                                                    float* __restrict__ pacc,
                                                    float* __restrict__ pz) {
    __shared__ __align__(16) u16 wbf[64 * 136];
    __shared__ __align__(16) u16 whT[48 * 128];   // rows 0..39 data, 40..47 zero
    __shared__ float f1s[64];
    const int t     = threadIdx.x;
    const int n0    = blockIdx.x * 64;
    const int chunk = blockIdx.y;
    const int mbase = chunk * 256;
    const int lane  = t & 63;
    const int l15   = lane & 15;
    const int q     = lane >> 4;
    const int wrow  = (t >> 6) * 16;
    const int c4    = (t & 31) * 4;
    const int rg    = t >> 5;
    const bf16x8 bones = ones_frag();
    if (t < 64) f1s[t] = F1o[n0 + t];
    // zero pad rows 40..47 (read by df=2 frag, lanes l15>=8); 8*128 = 1024
    #pragma unroll
    for (int i = 0; i < 4; ++i)
        whT[40 * 128 + t + 256 * i] = 0;

    // gl_lds staging: wave 0 rows 0..15 (4 insts), wave 1 rows 16..31 (4),
    // wave 2 rows 32..39 (2), wave 3 none. Source pre-swizzled.
    const int wv   = t >> 6;
    const int lsub = lane >> 4;
    const int slot = lane & 15;
    const int ninst = (wv < 2) ? 4 : ((wv == 2) ? 2 : 0);
    const u16* gsrc[4];
    #pragma unroll
    for (int i = 0; i < 4; ++i) {
        int row_l = wv * 16 + i * 4 + lsub;
        int rl    = (row_l < 40) ? row_l : 0;     // keep addr in-bounds for unused insts
        int sc    = (slot ^ ((i * 4 + lsub) & 7)) * 8;
        gsrc[i] = Wh2T + (size_t)rl * 4096 + sc;
    }
    u16* ldst = &whT[wv * 2048];
    const int xb7 = l15 & 7;

    f32x4 acc[4];
    #pragma unroll
    for (int df = 0; df < 4; ++df)
        #pragma unroll
        for (int r = 0; r < 4; ++r) acc[df][r] = 0.f;

    int4 aprev[8];
    #pragma unroll
    for (int i = 0; i < 8; ++i)
        aprev[i] = *(const int4*)&adj0[(size_t)(n0 + rg + 8 * i) * N + mbase + c4];
    __syncthreads();

    #pragma unroll
    for (int mt = 0; mt < 2; ++mt) {
        const int m0 = mbase + mt * 128;
        // ---- issue whT DMA for this tile ----
        #pragma unroll
        for (int i = 0; i < 4; ++i)
            if (i < ninst)
                gload_lds16(gsrc[i] + m0, ldst + i * 512);
        // ---- mask-gen ----
        float4 F2v = *(const float4*)&F2o[m0 + c4];
        #pragma unroll
        for (int i = 0; i < 8; ++i) {
            int rr = rg + 8 * i;
            int4 a4 = aprev[i];
            float f1v = f1s[rr];
            float w0 = mexp(a4.x, f1v + F2v.x);
            float w1 = mexp(a4.y, f1v + F2v.y);
            float w2 = mexp(a4.z, f1v + F2v.z);
            float w3 = mexp(a4.w, f1v + F2v.w);
            uint2 pk;
            pk.x = pk2(w0, w1);
            pk.y = pk2(w2, w3);
            *(uint2*)&wbf[rr * 136 + c4] = pk;
        }
        int mn = mbase + ((mt + 1) & 1) * 128;    // wrap harmless
        #pragma unroll
        for (int i = 0; i < 8; ++i)
            aprev[i] = *(const int4*)&adj0[(size_t)(n0 + rg + 8 * i) * N + mn + c4];
        __syncthreads();   // vmcnt(0) drain completes the DMA
        #pragma unroll
        for (int ks = 0; ks < 4; ++ks) {
            int k0 = ks * 32 + q * 8;
            bf16x8 a = *(const bf16x8*)&wbf[(wrow + l15) * 136 + k0];
            #pragma unroll
            for (int df = 0; df < 3; ++df) {
                bf16x8 b = *(const bf16x8*)
                    &whT[(df * 16 + l15) * 128 + (((ks * 4 + q) ^ xb7) * 8)];
                acc[df] = __builtin_amdgcn_mfma_f32_16x16x32_bf16(a, b, acc[df], 0, 0, 0);
            }
            acc[3] = __builtin_amdgcn_mfma_f32_16x16x32_bf16(a, bones, acc[3], 0, 0, 0);
        }
        __syncthreads();
    }
    #pragma unroll
    for (int r = 0; r < 4; ++r) {
        int n = n0 + wrow + q * 4 + r;
        if (l15 == 0) pz[(size_t)chunk * N + n] = acc[3][r];
        #pragma unroll
        for (int df = 0; df < 3; ++df) {
            int c = df * 16 + l15;
            if (c < NCLASS)
                pacc[((size_t)chunk * N + n) * NCLASS + c] = acc[df][r];
        }
    }
}

// ---------------- K5b: reduce 16 chunks, ELU, log_softmax, f32 store ------------
__global__ __launch_bounds__(256) void k5b_final(const float* __restrict__ pacc,
                                                 const float* __restrict__ pz,
                                                 float* __restrict__ out) {
    const int t = threadIdx.x;
    const int lane = t & 63;
    const int n = blockIdx.x * 4 + (t >> 6);
    float s = 0.f, Z = 0.f;
    #pragma unroll
    for (int ch = 0; ch < 16; ++ch) {
        Z += pz[(size_t)ch * N + n];
        if (lane < NCLASS) s += pacc[(size_t)(ch * N + n) * NCLASS + lane];
    }
    float v;
    if (lane < NCLASS) {
        v = s / fmaxf(Z, 1e-30f);
        v = v > 0.f ? v : __expf(v) - 1.f;
    } else {
        v = -INFINITY;
    }
    float mx = v;
    #pragma unroll
    for (int off = 32; off >= 1; off >>= 1) mx = fmaxf(mx, __shfl_xor(mx, off));
    float ex = (lane < NCLASS) ? __expf(v - mx) : 0.f;
    #pragma unroll
    for (int off = 32; off >= 1; off >>= 1) ex += __shfl_xor(ex, off);
    float lse = mx + __logf(ex);
    if (lane < NCLASS) out[(size_t)n * NCLASS + lane] = v - lse;
}

// ---------------------------------------------------------------------------------
extern "C" void kernel_launch(void* const* d_in, const int* in_sizes, int n_in,
                              void* d_out, int out_size, void* d_ws, size_t ws_size,
                              hipStream_t stream) {
    const float* x   = (const float*)d_in[0];
    const int*   adj = (const int*)d_in[1];
    const float* W1  = (const float*)d_in[2];
    const float* a1  = (const float*)d_in[3];
    const float* Wo  = (const float*)d_in[4];
    const float* ao  = (const float*)d_in[5];

    float* ws    = (float*)d_ws;
    float* h1    = ws;                        // 2,097,152
    float* F1    = h1 + 2097152;              // 32,768
    float* F2    = F1 + 32768;                // 32,768
    float* F1o   = F2 + 32768;                // 4,096
    float* F2o   = F1o + 4096;                // 4,096
    float* pz    = F2o + 4096;                // 65,536 (16*4096, k5a)
    float* pz1   = pz + 65536;                // 65,536 (unused now)
    u16*   Wh1T  = (u16*)(pz1 + 65536);       // 2,097,152 u16
    u16*   Wh2T  = Wh1T + 2097152;            // 163,840 u16
    float* R     = (float*)(Wh2T + 163840);   // 4,194,304 f32 shared region
    u16*   xb    = (u16*)R;                   // kcx -> k1m (dies before k3)
    u16*   W1b   = xb + 2097152;              // kcw -> k1m (dies before k3)
    float* pacc  = R;                         // k5a -> k5b (16*4096*40)

    const int* adj0 = adj;                    // layer-2 mask
    const int* adj1 = adj + (size_t)N * N;    // layer-1 mask

    hipLaunchKernelGGL(kcx,       dim3(1024),   dim3(256), 0, stream, x, xb);
    hipLaunchKernelGGL(kcw,       dim3(8, 8),   dim3(256), 0, stream, W1, W1b);
    hipLaunchKernelGGL(k1m_gemm1, dim3(64, 8),  dim3(256), 0, stream, xb, W1b, a1, Wh1T, F1, F2);
    hipLaunchKernelGGL(k3_attn1,  dim3(128, 8), dim3(256), 0, stream, adj1, Wh1T, F1, F2, h1);
    hipLaunchKernelGGL(k4_gemm2,  dim3(1024),   dim3(256), 0, stream, h1, Wo, ao, F1o, F2o, Wh2T);
    hipLaunchKernelGGL(k5a_attn2, dim3(64, 16), dim3(256), 0, stream, adj0, Wh2T, F1o, F2o, pacc, pz);
    hipLaunchKernelGGL(k5b_final, dim3(1024),   dim3(256), 0, stream, pacc, pz, (float*)d_out);
}

// Round 14
// 302.071 us; speedup vs baseline: 1.0829x; 1.0829x over previous
//
#include <hip/hip_runtime.h>
#include <hip/hip_bf16.h>

#define N      4096
#define NFEAT  512
#define NHID   64
#define NHEADS 8
#define NCLASS 40
#define ALPHA  0.2f
#define LOG2E  1.44269504f

typedef unsigned short u16;
typedef unsigned int   u32;
typedef __attribute__((ext_vector_type(8))) short bf16x8;
typedef __attribute__((ext_vector_type(4))) float f32x4;

// bf16 bits -> f32
__device__ __forceinline__ float b2f(u16 u) {
    return __uint_as_float(((u32)u) << 16);
}
// RNE-rounded value kept in HIGH 16 bits
__device__ __forceinline__ u32 rnd_hi(float f) {
    u32 u = __float_as_uint(f);
    return u + 0x7FFFu + ((u >> 16) & 1u);
}
// pack two f32 -> two bf16 (lo in low 16) via HW v_cvt_pk_bf16_f32 (gfx950)
__device__ __forceinline__ u32 pk2(float lo, float hi) {
    __hip_bfloat162 h = __float22bfloat162_rn(make_float2(lo, hi));
    return *(u32*)&h;
}
// single f32 -> bf16 bits (RNE)
__device__ __forceinline__ u16 f2b(float f) {
    return (u16)(rnd_hi(f) >> 16);
}
// masked exp2 of leaky-relu in log2 domain: raw v_exp_f32, no OCML guards
__device__ __forceinline__ float mexp(int m, float t) {
    return m ? __builtin_amdgcn_exp2f(fmaxf(t, ALPHA * t)) : 0.f;
}
// constant all-ones bf16 B-fragment (every output column = row sum)
__device__ __forceinline__ bf16x8 ones_frag() {
    union { u16 u[8]; bf16x8 v; } o;
    #pragma unroll
    for (int j = 0; j < 8; ++j) o.u[j] = 0x3F80;
    return o.v;
}
// async global->LDS DMA, 16B per lane; LDS dest = wave-uniform base + lane*16.
// Completion is guaranteed by the vmcnt(0) drain inside __syncthreads().
__device__ __forceinline__ void gload_lds16(const u16* g, u16* l) {
    __builtin_amdgcn_global_load_lds(
        (const __attribute__((address_space(1))) void*)g,
        (__attribute__((address_space(3))) void*)l,
        16, 0, 0);
}

// ---------------- KCX: x f32 -> xb bf16 (same layout) ---------------------------
__global__ __launch_bounds__(256) void kcx(const float* __restrict__ x,
                                           u16* __restrict__ xb) {
    const int g = blockIdx.x * 256 + threadIdx.x;       // 262144 threads x 8 elems
    const size_t base = (size_t)g * 8;
    float4 v0 = *(const float4*)&x[base];
    float4 v1 = *(const float4*)&x[base + 4];
    uint4 o;
    o.x = pk2(v0.x, v0.y); o.y = pk2(v0.z, v0.w);
    o.z = pk2(v1.x, v1.y); o.w = pk2(v1.z, v1.w);
    *(uint4*)&xb[base] = o;
}

// ---------------- KCW: W1 [h][f][d] f32 -> W1b bf16 [h][d][f] -------------------
__global__ __launch_bounds__(256) void kcw(const float* __restrict__ W1,
                                           u16* __restrict__ W1b) {
    __shared__ float ts[64 * 68];   // [f-local][d], pitch 68
    const int t  = threadIdx.x;
    const int f0 = blockIdx.x * 64;
    const int h  = blockIdx.y;
    #pragma unroll
    for (int i = 0; i < 4; ++i) {
        int flat = t + 256 * i;
        int row = flat >> 4;                    // f-local
        int c4  = (flat & 15) * 4;              // d
        *(float4*)&ts[row * 68 + c4] =
            *(const float4*)&W1[((size_t)h * 512 + f0 + row) * 64 + c4];
    }
    __syncthreads();
    const int d  = t >> 2;
    const int fs = (t & 3) * 16;
    u32 p[8];
    #pragma unroll
    for (int j = 0; j < 8; ++j)
        p[j] = pk2(ts[(fs + 2 * j) * 68 + d], ts[(fs + 2 * j + 1) * 68 + d]);
    u32* dst = (u32*)&W1b[((size_t)(h * 64 + d)) * 512 + f0 + fs];
    *(uint4*)dst       = make_uint4(p[0], p[1], p[2], p[3]);
    *(uint4*)(dst + 4) = make_uint4(p[4], p[5], p[6], p[7]);
}

// ---------------- K1M: Wh1T bf16 + fused F1/F2 epilogue -------------------------
// Round-7 proven version: gl_lds DMA double-buffered staging, XOR swizzle,
// one barrier per K-step. LDS 32 KB. grid (64 n-tiles, 8 heads) x 256.
__global__ __launch_bounds__(256, 4) void k1m_gemm1(const u16* __restrict__ xb,
                                                    const u16* __restrict__ W1b,
                                                    const float* __restrict__ a1,
                                                    u16* __restrict__ Wh1T,
                                                    float* __restrict__ F1,
                                                    float* __restrict__ F2) {
    __shared__ __align__(16) u16 xs[2][64 * 64];    // [n-local][f-chunk]
    __shared__ __align__(16) u16 wvs[2][64 * 64];   // [d][f-chunk]
    const int t    = threadIdx.x;
    const int n0   = blockIdx.x * 64;
    const int h    = blockIdx.y;
    const int lane = t & 63;
    const int l15  = lane & 15;
    const int q    = lane >> 4;
    const int wv   = t >> 6;
    const int wrow = wv * 16;
    const int lsub = lane >> 3;        // row-sub 0..7
    const int slot = lane & 7;         // 16B col slot 0..7
    const int xb7  = l15 & 7;          // read-side swizzle key

    // DMA sources, pre-swizzled: LDS[r][slot] = G[r][slot ^ (r&7)]; r&7 == lsub
    const u16* gx[2];
    const u16* gw[2];
    #pragma unroll
    for (int i = 0; i < 2; ++i) {
        const int r  = wv * 16 + i * 8 + lsub;
        const int sc = (slot ^ lsub) * 8;
        gx[i] = xb  + (size_t)(n0 + r) * 512 + sc;
        gw[i] = W1b + ((size_t)(h * 64 + r)) * 512 + sc;
    }

    f32x4 acc[4];
    #pragma unroll
    for (int df = 0; df < 4; ++df)
        #pragma unroll
        for (int r = 0; r < 4; ++r) acc[df][r] = 0.f;

#define K1_DMA(P, F0)                                                          \
    {                                                                          \
        _Pragma("unroll")                                                      \
        for (int i = 0; i < 2; ++i) {                                          \
            gload_lds16(gx[i] + (F0), &xs[P][(wv * 16 + i * 8) * 64]);         \
            gload_lds16(gw[i] + (F0), &wvs[P][(wv * 16 + i * 8) * 64]);        \
        }                                                                      \
    }
#define K1_MFMA(P)                                                            \
    {                                                                          \
        _Pragma("unroll")                                                      \
        for (int ks = 0; ks < 2; ++ks) {                                       \
            const int sl = ((ks * 4 + q) ^ xb7) * 8;                           \
            bf16x8 a = *(const bf16x8*)&xs[P][(wrow + l15) * 64 + sl];         \
            _Pragma("unroll")                                                  \
            for (int df = 0; df < 4; ++df) {                                   \
                bf16x8 b = *(const bf16x8*)&wvs[P][(df * 16 + l15) * 64 + sl]; \
                acc[df] = __builtin_amdgcn_mfma_f32_16x16x32_bf16(a, b, acc[df], 0, 0, 0); \
            }                                                                  \
        }                                                                      \
    }

    K1_DMA(0, 0)
    __syncthreads();
    for (int f0 = 0; f0 < 512; f0 += 128) {
        K1_DMA(1, f0 + 64)          // covered by MFMA(0) + other waves
        K1_MFMA(0)
        __syncthreads();            // drains DMA -> buf1 ready
        if (f0 + 128 < 512)
            K1_DMA(0, f0 + 128)
        K1_MFMA(1)
        __syncthreads();
    }
#undef K1_DMA
#undef K1_MFMA

    // Wh1T store: C row = q*4+r (n-local), col = l15 (d-local)
    #pragma unroll
    for (int df = 0; df < 4; ++df) {
        uint2 o;
        o.x = pk2(acc[df][0], acc[df][1]);
        o.y = pk2(acc[df][2], acc[df][3]);
        *(uint2*)&Wh1T[((size_t)(h * 64 + df * 16 + l15)) * 4096 + n0 + wrow + q * 4] = o;
    }
    // fused F1/F2: f = sum_d Wh[n][h*64+d] * a1[h,{0,1},d], reduce over l15 group
    float a1v[4], a2v[4];
    #pragma unroll
    for (int df = 0; df < 4; ++df) {
        a1v[df] = a1[h * 128 + df * 16 + l15];
        a2v[df] = a1[h * 128 + 64 + df * 16 + l15];
    }
    #pragma unroll
    for (int r = 0; r < 4; ++r) {
        float s1 = 0.f, s2 = 0.f;
        #pragma unroll
        for (int df = 0; df < 4; ++df) {
            s1 += acc[df][r] * a1v[df];
            s2 += acc[df][r] * a2v[df];
        }
        #pragma unroll
        for (int off = 8; off >= 1; off >>= 1) {
            s1 += __shfl_xor(s1, off);
            s2 += __shfl_xor(s2, off);
        }
        if (l15 == 0) {
            int n = n0 + wrow + q * 4 + r;
            F1[h * 4096 + n] = s1 * LOG2E;
            F2[h * 4096 + n] = s2 * LOG2E;
        }
    }
}

// ---------------- K3: layer-1 attention, fused, 32-row tiles --------------------
// Round-7 proven version (measured 78 us; declared structural floor after the
// r8-r13 matrix: VALU-cut, conflict-cut, occupancy up/down, barrier-halving,
// counted-vmcnt all null-to-negative). LDS 24.8 KB -> 4 blocks/CU.
// grid (128 n-tiles, 8 heads) x 256.
__global__ __launch_bounds__(256, 4) void k3_attn1(const int* __restrict__ adj1,
                                                   const u16* __restrict__ Wh1T,
                                                   const float* __restrict__ F1,
                                                   const float* __restrict__ F2,
                                                   float* __restrict__ h1) {
    __shared__ __align__(16) u16 wbf[32 * 136];   // A-tile, pitch 136
    __shared__ __align__(16) u16 whT[64 * 128];   // B-tile, linear+swizzled
    __shared__ float f1s[32];
    __shared__ float zs[32];
    const int t     = threadIdx.x;
    const int n0    = blockIdx.x * 32;
    const int h     = blockIdx.y;
    const int lane  = t & 63;
    const int l15   = lane & 15;
    const int q     = lane >> 4;
    const int wv    = t >> 6;
    const int rb    = (wv & 1) * 16;          // row-block base
    const int dh    = wv >> 1;                // df-half: computes df = dh*2+j
    const int c4    = (t & 31) * 4;           // mask-gen: 4 consecutive cols
    const int rg    = t >> 5;                 // mask-gen: row group 0..7
    const bf16x8 bones = ones_frag();
    if (t < 32) f1s[t] = F1[h * N + n0 + t];

    // gl_lds staging map (whT = head's full 64 d-rows): wave wv, inst i covers
    // rows wv*16+i*4 .. +3; source pre-swizzled slot j = slot^(row&7)
    const int lsub = lane >> 4;
    const int slot = lane & 15;
    const u16* gsrc[4];
    #pragma unroll
    for (int i = 0; i < 4; ++i) {
        int row_l = wv * 16 + i * 4 + lsub;
        int sc    = (slot ^ ((i * 4 + lsub) & 7)) * 8;
        gsrc[i] = Wh1T + ((size_t)(h * 64 + row_l)) * 4096 + sc;
    }
    u16* ldst = &whT[wv * 2048];              // + i*512 per inst (wave-uniform)
    const int xb7 = l15 & 7;                  // read-side swizzle key

    f32x4 accd[2], accz;
    #pragma unroll
    for (int j = 0; j < 2; ++j)
        #pragma unroll
        for (int r = 0; r < 4; ++r) accd[j][r] = 0.f;
    #pragma unroll
    for (int r = 0; r < 4; ++r) accz[r] = 0.f;

    // initial prefetch: iter-0 adj tile (4 rows/thread) + F2 vector
    int4 aprev[4];
    #pragma unroll
    for (int i = 0; i < 4; ++i)
        aprev[i] = *(const int4*)&adj1[(size_t)(n0 + rg + 8 * i) * N + c4];
    float4 f2n = *(const float4*)&F2[h * N + c4];
    __syncthreads();

    for (int m0 = 0; m0 < 4096; m0 += 128) {
        // ---- issue whT DMA for this tile (covered by mask-gen VALU) ----
        #pragma unroll
        for (int i = 0; i < 4; ++i)
            gload_lds16(gsrc[i] + m0, ldst + i * 512);
        // ---- mask-gen; consume aprev[i], immediately issue its replacement ----
        const float4 F2v = f2n;
        const int mn = (m0 + 128 < 4096) ? m0 + 128 : 0;   // wrap harmless
        f2n = *(const float4*)&F2[h * N + mn + c4];
        #pragma unroll
        for (int i = 0; i < 4; ++i) {
            const int rr = rg + 8 * i;
            int4 a4 = aprev[i];
            aprev[i] = *(const int4*)&adj1[(size_t)(n0 + rr) * N + mn + c4];
            float f1v = f1s[rr];
            float w0 = mexp(a4.x, f1v + F2v.x);
            float w1 = mexp(a4.y, f1v + F2v.y);
            float w2 = mexp(a4.z, f1v + F2v.z);
            float w3 = mexp(a4.w, f1v + F2v.w);
            uint2 pk;
            pk.x = pk2(w0, w1);
            pk.y = pk2(w2, w3);
            *(uint2*)&wbf[rr * 136 + c4] = pk;
        }
        __syncthreads();   // vmcnt(0) drain: DMA + prefetches already covered
        // ---- compute: 4 K-steps x (2 data frags + ones frag on dh==0) ----
        #pragma unroll
        for (int ks = 0; ks < 4; ++ks) {
            int k0 = ks * 32 + q * 8;
            bf16x8 a = *(const bf16x8*)&wbf[(rb + l15) * 136 + k0];
            #pragma unroll
            for (int j = 0; j < 2; ++j) {
                const int df = dh * 2 + j;
                bf16x8 b = *(const bf16x8*)
                    &whT[(df * 16 + l15) * 128 + (((ks * 4 + q) ^ xb7) * 8)];
                accd[j] = __builtin_amdgcn_mfma_f32_16x16x32_bf16(a, b, accd[j], 0, 0, 0);
            }
            if (dh == 0)
                accz = __builtin_amdgcn_mfma_f32_16x16x32_bf16(a, bones, accz, 0, 0, 0);
        }
        __syncthreads();
    }
    // denominator broadcast across the df-split, then normalize + ELU -> h1
    if (dh == 0 && l15 == 0) {
        #pragma unroll
        for (int r = 0; r < 4; ++r) zs[rb + q * 4 + r] = accz[r];
    }
    __syncthreads();
    #pragma unroll
    for (int r = 0; r < 4; ++r) {
        const int nl = rb + q * 4 + r;
        const float z = fmaxf(zs[nl], 1e-30f);
        #pragma unroll
        for (int j = 0; j < 2; ++j) {
            float v = accd[j][r] / z;
            v = v > 0.f ? v : __expf(v) - 1.f;
            h1[(size_t)(n0 + nl) * 512 + h * 64 + (dh * 2 + j) * 16 + l15] = v;
        }
    }
}

// ---------------- K4: fused Wh2 GEMM + F1o/F2o + Wh2T bf16 ----------------------
// wave = one n (lane = c); grid 1024 x 256.
__global__ __launch_bounds__(256) void k4_gemm2(const float* __restrict__ h1,
                                                const float* __restrict__ Wo,
                                                const float* __restrict__ ao,
                                                float* __restrict__ F1o,
                                                float* __restrict__ F2o,
                                                u16* __restrict__ Wh2T) {
    const int t = threadIdx.x;
    const int c = t & 63;
    const int n = blockIdx.x * 4 + (t >> 6);
    float acc = 0.f;
    if (c < NCLASS) {
        const float* hrow = &h1[(size_t)n * 512];
        #pragma unroll 8
        for (int f = 0; f < 512; ++f)
            acc += hrow[f] * Wo[f * NCLASS + c];
        Wh2T[(size_t)c * 4096 + n] = f2b(acc);
    }
    float s1 = (c < NCLASS) ? acc * ao[c] : 0.f;
    float s2 = (c < NCLASS) ? acc * ao[NCLASS + c] : 0.f;
    #pragma unroll
    for (int off = 32; off >= 1; off >>= 1) {
        s1 += __shfl_xor(s1, off);
        s2 += __shfl_xor(s2, off);
    }
    if (c == 0) {
        F1o[n] = s1 * LOG2E;
        F2o[n] = s2 * LOG2E;
    }
}

// ---------------- K5a: layer-2 attention, k3-r7 skeleton transplant -------------
// 32-row n-tiles x 8 m-chunks (512 cols, 4 iters/block): prologue amortized 2x
// vs the old 2-iter form, pacc/pz halved. Proven consume-then-issue adj/F2
// rotation + gl_lds/swizzle whT staging. Wave split: rb=(wv&1)*16 rows;
// dh=0 -> df0 + ones-denominator, dh=1 -> df1 + df2 (balanced, wave-uniform).
// LDS 21.2 KB -> 4 blocks/CU at grid (128, 8) = 1024 blocks.
__global__ __launch_bounds__(256, 4) void k5a_attn2(const int* __restrict__ adj0,
                                                    const u16* __restrict__ Wh2T,
                                                    const float* __restrict__ F1o,
                                                    const float* __restrict__ F2o,
                                                    float* __restrict__ pacc,
                                                    float* __restrict__ pz) {
    __shared__ __align__(16) u16 wbf[32 * 136];   // A-tile, pitch 136
    __shared__ __align__(16) u16 whT[48 * 128];   // rows 0..39 data, 40..47 zero
    __shared__ float f1s[32];
    const int t     = threadIdx.x;
    const int n0    = blockIdx.x * 32;
    const int chunk = blockIdx.y;                 // 0..7
    const int mbase = chunk * 512;
    const int lane  = t & 63;
    const int l15   = lane & 15;
    const int q     = lane >> 4;
    const int wv    = t >> 6;
    const int rb    = (wv & 1) * 16;              // row-block base
    const int dh    = wv >> 1;                    // 0: df0+ones, 1: df1+df2
    const int c4    = (t & 31) * 4;
    const int rg    = t >> 5;                     // mask-gen row group 0..7
    const bf16x8 bones = ones_frag();
    if (t < 32) f1s[t] = F1o[n0 + t];
    // zero pad rows 40..47 (read by df=2 frag, lanes l15>=8); 8*128 = 1024
    #pragma unroll
    for (int i = 0; i < 4; ++i)
        whT[40 * 128 + t + 256 * i] = 0;

    // gl_lds staging: wave 0 rows 0..15 (4 insts), wave 1 rows 16..31 (4),
    // wave 2 rows 32..39 (2), wave 3 none. Source pre-swizzled.
    const int lsub = lane >> 4;
    const int slot = lane & 15;
    const int ninst = (wv < 2) ? 4 : ((wv == 2) ? 2 : 0);
    const u16* gsrc[4];
    #pragma unroll
    for (int i = 0; i < 4; ++i) {
        int row_l = wv * 16 + i * 4 + lsub;
        int rl    = (row_l < 40) ? row_l : 0;     // keep addr in-bounds for unused insts
        int sc    = (slot ^ ((i * 4 + lsub) & 7)) * 8;
        gsrc[i] = Wh2T + (size_t)rl * 4096 + sc;
    }
    u16* ldst = &whT[wv * 2048];
    const int xb7 = l15 & 7;

    f32x4 acc0, acc1, accz;
    #pragma unroll
    for (int r = 0; r < 4; ++r) { acc0[r] = 0.f; acc1[r] = 0.f; accz[r] = 0.f; }

    // initial prefetch: iter-0 adj tile (4 rows/thread) + F2 vector
    int4 aprev[4];
    #pragma unroll
    for (int i = 0; i < 4; ++i)
        aprev[i] = *(const int4*)&adj0[(size_t)(n0 + rg + 8 * i) * N + mbase + c4];
    float4 f2n = *(const float4*)&F2o[mbase + c4];
    __syncthreads();

    for (int it = 0; it < 4; ++it) {
        const int m0 = mbase + it * 128;
        // ---- issue whT DMA for this tile (covered by mask-gen VALU) ----
        #pragma unroll
        for (int i = 0; i < 4; ++i)
            if (i < ninst)
                gload_lds16(gsrc[i] + m0, ldst + i * 512);
        // ---- mask-gen; consume aprev[i], immediately issue its replacement ----
        const float4 F2v = f2n;
        const int mn = (it < 3) ? m0 + 128 : mbase;   // wrap harmless
        f2n = *(const float4*)&F2o[mn + c4];
        #pragma unroll
        for (int i = 0; i < 4; ++i) {
            const int rr = rg + 8 * i;
            int4 a4 = aprev[i];
            aprev[i] = *(const int4*)&adj0[(size_t)(n0 + rr) * N + mn + c4];
            float f1v = f1s[rr];
            float w0 = mexp(a4.x, f1v + F2v.x);
            float w1 = mexp(a4.y, f1v + F2v.y);
            float w2 = mexp(a4.z, f1v + F2v.z);
            float w3 = mexp(a4.w, f1v + F2v.w);
            uint2 pk;
            pk.x = pk2(w0, w1);
            pk.y = pk2(w2, w3);
            *(uint2*)&wbf[rr * 136 + c4] = pk;
        }
        __syncthreads();   // vmcnt(0) drain: DMA + prefetches already covered
        // ---- compute: 4 K-steps x 2 MFMAs per wave (wave-uniform dh split) ----
        #pragma unroll
        for (int ks = 0; ks < 4; ++ks) {
            int k0 = ks * 32 + q * 8;
            bf16x8 a = *(const bf16x8*)&wbf[(rb + l15) * 136 + k0];
            const int sl = (((ks * 4 + q) ^ xb7) * 8);
            if (dh == 0) {
                bf16x8 b0 = *(const bf16x8*)&whT[(0 * 16 + l15) * 128 + sl];
                acc0 = __builtin_amdgcn_mfma_f32_16x16x32_bf16(a, b0, acc0, 0, 0, 0);
                accz = __builtin_amdgcn_mfma_f32_16x16x32_bf16(a, bones, accz, 0, 0, 0);
            } else {
                bf16x8 b1 = *(const bf16x8*)&whT[(1 * 16 + l15) * 128 + sl];
                acc0 = __builtin_amdgcn_mfma_f32_16x16x32_bf16(a, b1, acc0, 0, 0, 0);
                bf16x8 b2 = *(const bf16x8*)&whT[(2 * 16 + l15) * 128 + sl];
                acc1 = __builtin_amdgcn_mfma_f32_16x16x32_bf16(a, b2, acc1, 0, 0, 0);
            }
        }
        __syncthreads();
    }
    // write partials: dh=0 -> cols 0..15 + pz; dh=1 -> cols 16..39
    #pragma unroll
    for (int r = 0; r < 4; ++r) {
        const int n = n0 + rb + q * 4 + r;
        const size_t base = ((size_t)chunk * N + n) * NCLASS;
        if (dh == 0) {
            if (l15 == 0) pz[(size_t)chunk * N + n] = accz[r];
            pacc[base + l15] = acc0[r];
        } else {
            pacc[base + 16 + l15] = acc0[r];
            if (l15 < 8) pacc[base + 32 + l15] = acc1[r];
        }
    }
}

// ---------------- K5b: reduce 8 chunks, ELU, log_softmax, f32 store -------------
__global__ __launch_bounds__(256) void k5b_final(const float* __restrict__ pacc,
                                                 const float* __restrict__ pz,
                                                 float* __restrict__ out) {
    const int t = threadIdx.x;
    const int lane = t & 63;
    const int n = blockIdx.x * 4 + (t >> 6);
    float s = 0.f, Z = 0.f;
    #pragma unroll
    for (int ch = 0; ch < 8; ++ch) {
        Z += pz[(size_t)ch * N + n];
        if (lane < NCLASS) s += pacc[(size_t)(ch * N + n) * NCLASS + lane];
    }
    float v;
    if (lane < NCLASS) {
        v = s / fmaxf(Z, 1e-30f);
        v = v > 0.f ? v : __expf(v) - 1.f;
    } else {
        v = -INFINITY;
    }
    float mx = v;
    #pragma unroll
    for (int off = 32; off >= 1; off >>= 1) mx = fmaxf(mx, __shfl_xor(mx, off));
    float ex = (lane < NCLASS) ? __expf(v - mx) : 0.f;
    #pragma unroll
    for (int off = 32; off >= 1; off >>= 1) ex += __shfl_xor(ex, off);
    float lse = mx + __logf(ex);
    if (lane < NCLASS) out[(size_t)n * NCLASS + lane] = v - lse;
}

// ---------------------------------------------------------------------------------
extern "C" void kernel_launch(void* const* d_in, const int* in_sizes, int n_in,
                              void* d_out, int out_size, void* d_ws, size_t ws_size,
                              hipStream_t stream) {
    const float* x   = (const float*)d_in[0];
    const int*   adj = (const int*)d_in[1];
    const float* W1  = (const float*)d_in[2];
    const float* a1  = (const float*)d_in[3];
    const float* Wo  = (const float*)d_in[4];
    const float* ao  = (const float*)d_in[5];

    float* ws    = (float*)d_ws;
    float* h1    = ws;                        // 2,097,152
    float* F1    = h1 + 2097152;              // 32,768
    float* F2    = F1 + 32768;                // 32,768
    float* F1o   = F2 + 32768;                // 4,096
    float* F2o   = F1o + 4096;                // 4,096
    float* pz    = F2o + 4096;                // 32,768 (8*4096, k5a)
    float* pz1   = pz + 65536;                // 65,536 (unused)
    u16*   Wh1T  = (u16*)(pz1 + 65536);       // 2,097,152 u16
    u16*   Wh2T  = Wh1T + 2097152;            // 163,840 u16
    float* R     = (float*)(Wh2T + 163840);   // 4,194,304 f32 shared region
    u16*   xb    = (u16*)R;                   // kcx -> k1m (dies before k3)
    u16*   W1b   = xb + 2097152;              // kcw -> k1m (dies before k3)
    float* pacc  = R;                         // k5a -> k5b (8*4096*40)

    const int* adj0 = adj;                    // layer-2 mask
    const int* adj1 = adj + (size_t)N * N;    // layer-1 mask

    hipLaunchKernelGGL(kcx,       dim3(1024),   dim3(256), 0, stream, x, xb);
    hipLaunchKernelGGL(kcw,       dim3(8, 8),   dim3(256), 0, stream, W1, W1b);
    hipLaunchKernelGGL(k1m_gemm1, dim3(64, 8),  dim3(256), 0, stream, xb, W1b, a1, Wh1T, F1, F2);
    hipLaunchKernelGGL(k3_attn1,  dim3(128, 8), dim3(256), 0, stream, adj1, Wh1T, F1, F2, h1);
    hipLaunchKernelGGL(k4_gemm2,  dim3(1024),   dim3(256), 0, stream, h1, Wo, ao, F1o, F2o, Wh2T);
    hipLaunchKernelGGL(k5a_attn2, dim3(128, 8), dim3(256), 0, stream, adj0, Wh2T, F1o, F2o, pacc, pz);
    hipLaunchKernelGGL(k5b_final, dim3(1024),   dim3(256), 0, stream, pacc, pz, (float*)d_out);
}

// Round 15
// 300.210 us; speedup vs baseline: 1.0896x; 1.0062x over previous
//
#include <hip/hip_runtime.h>
#include <hip/hip_bf16.h>

#define N      4096
#define NFEAT  512
#define NHID   64
#define NHEADS 8
#define NCLASS 40
#define ALPHA  0.2f
#define LOG2E  1.44269504f

typedef unsigned short u16;
typedef unsigned int   u32;
typedef __attribute__((ext_vector_type(8))) short bf16x8;
typedef __attribute__((ext_vector_type(4))) float f32x4;

// bf16 bits -> f32
__device__ __forceinline__ float b2f(u16 u) {
    return __uint_as_float(((u32)u) << 16);
}
// RNE-rounded value kept in HIGH 16 bits
__device__ __forceinline__ u32 rnd_hi(float f) {
    u32 u = __float_as_uint(f);
    return u + 0x7FFFu + ((u >> 16) & 1u);
}
// pack two f32 -> two bf16 (lo in low 16) via HW v_cvt_pk_bf16_f32 (gfx950)
__device__ __forceinline__ u32 pk2(float lo, float hi) {
    __hip_bfloat162 h = __float22bfloat162_rn(make_float2(lo, hi));
    return *(u32*)&h;
}
// single f32 -> bf16 bits (RNE)
__device__ __forceinline__ u16 f2b(float f) {
    return (u16)(rnd_hi(f) >> 16);
}
// masked exp2 of leaky-relu in log2 domain: raw v_exp_f32, no OCML guards
__device__ __forceinline__ float mexp(int m, float t) {
    return m ? __builtin_amdgcn_exp2f(fmaxf(t, ALPHA * t)) : 0.f;
}
// constant all-ones bf16 B-fragment (every output column = row sum)
__device__ __forceinline__ bf16x8 ones_frag() {
    union { u16 u[8]; bf16x8 v; } o;
    #pragma unroll
    for (int j = 0; j < 8; ++j) o.u[j] = 0x3F80;
    return o.v;
}
// async global->LDS DMA, 16B per lane; LDS dest = wave-uniform base + lane*16.
// Completion is guaranteed by the vmcnt(0) drain inside __syncthreads().
__device__ __forceinline__ void gload_lds16(const u16* g, u16* l) {
    __builtin_amdgcn_global_load_lds(
        (const __attribute__((address_space(1))) void*)g,
        (__attribute__((address_space(3))) void*)l,
        16, 0, 0);
}

// ---------------- KCX: x f32 -> xb bf16 (same layout) ---------------------------
__global__ __launch_bounds__(256) void kcx(const float* __restrict__ x,
                                           u16* __restrict__ xb) {
    const int g = blockIdx.x * 256 + threadIdx.x;       // 262144 threads x 8 elems
    const size_t base = (size_t)g * 8;
    float4 v0 = *(const float4*)&x[base];
    float4 v1 = *(const float4*)&x[base + 4];
    uint4 o;
    o.x = pk2(v0.x, v0.y); o.y = pk2(v0.z, v0.w);
    o.z = pk2(v1.x, v1.y); o.w = pk2(v1.z, v1.w);
    *(uint4*)&xb[base] = o;
}

// ---------------- KCW: W1 [h][f][d] f32 -> W1b bf16 [h][d][f] -------------------
__global__ __launch_bounds__(256) void kcw(const float* __restrict__ W1,
                                           u16* __restrict__ W1b) {
    __shared__ float ts[64 * 68];   // [f-local][d], pitch 68
    const int t  = threadIdx.x;
    const int f0 = blockIdx.x * 64;
    const int h  = blockIdx.y;
    #pragma unroll
    for (int i = 0; i < 4; ++i) {
        int flat = t + 256 * i;
        int row = flat >> 4;                    // f-local
        int c4  = (flat & 15) * 4;              // d
        *(float4*)&ts[row * 68 + c4] =
            *(const float4*)&W1[((size_t)h * 512 + f0 + row) * 64 + c4];
    }
    __syncthreads();
    const int d  = t >> 2;
    const int fs = (t & 3) * 16;
    u32 p[8];
    #pragma unroll
    for (int j = 0; j < 8; ++j)
        p[j] = pk2(ts[(fs + 2 * j) * 68 + d], ts[(fs + 2 * j + 1) * 68 + d]);
    u32* dst = (u32*)&W1b[((size_t)(h * 64 + d)) * 512 + f0 + fs];
    *(uint4*)dst       = make_uint4(p[0], p[1], p[2], p[3]);
    *(uint4*)(dst + 4) = make_uint4(p[4], p[5], p[6], p[7]);
}

// ---------------- K1M: Wh1T bf16 + fused F1/F2 epilogue, 32-row tiles -----------
// Occupancy regrid of the round-7 version (proven k3/k5a geometry): 32-row
// n-tiles, grid (128, 8) = 1024 blocks = 4 blocks/CU (was 2). Wave split
// rb=(wv&1)*16 rows, dh=wv>>1 df-half. Same gl_lds dbuf + XOR swizzle. The
// F1/F2 df-sum spans dh waves -> 2-partial LDS combine (+1 barrier).
// LDS 24.5 KB. K-accumulation order unchanged.
__global__ __launch_bounds__(256, 4) void k1m_gemm1(const u16* __restrict__ xb,
                                                    const u16* __restrict__ W1b,
                                                    const float* __restrict__ a1,
                                                    u16* __restrict__ Wh1T,
                                                    float* __restrict__ F1,
                                                    float* __restrict__ F2) {
    __shared__ __align__(16) u16 xs[2][32 * 64];    // [n-local][f-chunk]
    __shared__ __align__(16) u16 wvs[2][64 * 64];   // [d][f-chunk]
    __shared__ float fp[2][2][32];                  // [s1|s2][dh][row]
    const int t    = threadIdx.x;
    const int n0   = blockIdx.x * 32;
    const int h    = blockIdx.y;
    const int lane = t & 63;
    const int l15  = lane & 15;
    const int q    = lane >> 4;
    const int wv   = t >> 6;
    const int rb   = (wv & 1) * 16;    // row-block base
    const int dh   = wv >> 1;          // df-half: df = dh*2+j
    const int lsub = lane >> 3;        // row-sub 0..7
    const int slot = lane & 7;         // 16B col slot 0..7
    const int xb7  = l15 & 7;          // read-side swizzle key

    // DMA sources, pre-swizzled: LDS[r][slot] = G[r][slot ^ (r&7)]; r&7 == lsub
    // xs: wave wv stages rows wv*8..+7 (1 inst); wvs: rows wv*16..+15 (2 insts)
    const u16* gx = xb + (size_t)(n0 + wv * 8 + lsub) * 512 + (slot ^ lsub) * 8;
    const u16* gw[2];
    #pragma unroll
    for (int i = 0; i < 2; ++i)
        gw[i] = W1b + ((size_t)(h * 64 + wv * 16 + i * 8 + lsub)) * 512
                    + (slot ^ lsub) * 8;

    f32x4 acc[2];
    #pragma unroll
    for (int j = 0; j < 2; ++j)
        #pragma unroll
        for (int r = 0; r < 4; ++r) acc[j][r] = 0.f;

#define K1_DMA(P, F0)                                                          \
    {                                                                          \
        gload_lds16(gx + (F0), &xs[P][(wv * 8) * 64]);                         \
        _Pragma("unroll")                                                      \
        for (int i = 0; i < 2; ++i)                                            \
            gload_lds16(gw[i] + (F0), &wvs[P][(wv * 16 + i * 8) * 64]);        \
    }
#define K1_MFMA(P)                                                            \
    {                                                                          \
        _Pragma("unroll")                                                      \
        for (int ks = 0; ks < 2; ++ks) {                                       \
            const int sl = ((ks * 4 + q) ^ xb7) * 8;                           \
            bf16x8 a = *(const bf16x8*)&xs[P][(rb + l15) * 64 + sl];           \
            _Pragma("unroll")                                                  \
            for (int j = 0; j < 2; ++j) {                                      \
                bf16x8 b = *(const bf16x8*)                                    \
                    &wvs[P][((dh * 2 + j) * 16 + l15) * 64 + sl];              \
                acc[j] = __builtin_amdgcn_mfma_f32_16x16x32_bf16(a, b, acc[j], 0, 0, 0); \
            }                                                                  \
        }                                                                      \
    }

    K1_DMA(0, 0)
    __syncthreads();
    for (int f0 = 0; f0 < 512; f0 += 128) {
        K1_DMA(1, f0 + 64)          // covered by MFMA(0) + other waves
        K1_MFMA(0)
        __syncthreads();            // drains DMA -> buf1 ready
        if (f0 + 128 < 512)
            K1_DMA(0, f0 + 128)
        K1_MFMA(1)
        __syncthreads();
    }
#undef K1_DMA
#undef K1_MFMA

    // Wh1T store: C row = q*4+r (n-local), col = l15 (d-local), df = dh*2+j
    #pragma unroll
    for (int j = 0; j < 2; ++j) {
        uint2 o;
        o.x = pk2(acc[j][0], acc[j][1]);
        o.y = pk2(acc[j][2], acc[j][3]);
        *(uint2*)&Wh1T[((size_t)(h * 64 + (dh * 2 + j) * 16 + l15)) * 4096
                       + n0 + rb + q * 4] = o;
    }
    // fused F1/F2: per-dh partial over its 2 dfs, shfl-reduce over l15,
    // then cross-wave combine via LDS.
    float a1v[2], a2v[2];
    #pragma unroll
    for (int j = 0; j < 2; ++j) {
        a1v[j] = a1[h * 128 + (dh * 2 + j) * 16 + l15];
        a2v[j] = a1[h * 128 + 64 + (dh * 2 + j) * 16 + l15];
    }
    #pragma unroll
    for (int r = 0; r < 4; ++r) {
        float s1 = 0.f, s2 = 0.f;
        #pragma unroll
        for (int j = 0; j < 2; ++j) {
            s1 += acc[j][r] * a1v[j];
            s2 += acc[j][r] * a2v[j];
        }
        #pragma unroll
        for (int off = 8; off >= 1; off >>= 1) {
            s1 += __shfl_xor(s1, off);
            s2 += __shfl_xor(s2, off);
        }
        if (l15 == 0) {
            fp[0][dh][rb + q * 4 + r] = s1;
            fp[1][dh][rb + q * 4 + r] = s2;
        }
    }
    __syncthreads();
    if (t < 32) {
        F1[h * 4096 + n0 + t] = (fp[0][0][t] + fp[0][1][t]) * LOG2E;
        F2[h * 4096 + n0 + t] = (fp[1][0][t] + fp[1][1][t]) * LOG2E;
    }
}

// ---------------- K3: layer-1 attention, fused, 32-row tiles --------------------
// Round-7 proven version (measured 78 us; declared structural floor after the
// r8-r13 matrix: VALU-cut, conflict-cut, occupancy up/down, barrier-halving,
// counted-vmcnt all null-to-negative). LDS 24.8 KB -> 4 blocks/CU.
// grid (128 n-tiles, 8 heads) x 256.
__global__ __launch_bounds__(256, 4) void k3_attn1(const int* __restrict__ adj1,
                                                   const u16* __restrict__ Wh1T,
                                                   const float* __restrict__ F1,
                                                   const float* __restrict__ F2,
                                                   float* __restrict__ h1) {
    __shared__ __align__(16) u16 wbf[32 * 136];   // A-tile, pitch 136
    __shared__ __align__(16) u16 whT[64 * 128];   // B-tile, linear+swizzled
    __shared__ float f1s[32];
    __shared__ float zs[32];
    const int t     = threadIdx.x;
    const int n0    = blockIdx.x * 32;
    const int h     = blockIdx.y;
    const int lane  = t & 63;
    const int l15   = lane & 15;
    const int q     = lane >> 4;
    const int wv    = t >> 6;
    const int rb    = (wv & 1) * 16;          // row-block base
    const int dh    = wv >> 1;                // df-half: computes df = dh*2+j
    const int c4    = (t & 31) * 4;           // mask-gen: 4 consecutive cols
    const int rg    = t >> 5;                 // mask-gen: row group 0..7
    const bf16x8 bones = ones_frag();
    if (t < 32) f1s[t] = F1[h * N + n0 + t];

    // gl_lds staging map (whT = head's full 64 d-rows): wave wv, inst i covers
    // rows wv*16+i*4 .. +3; source pre-swizzled slot j = slot^(row&7)
    const int lsub = lane >> 4;
    const int slot = lane & 15;
    const u16* gsrc[4];
    #pragma unroll
    for (int i = 0; i < 4; ++i) {
        int row_l = wv * 16 + i * 4 + lsub;
        int sc    = (slot ^ ((i * 4 + lsub) & 7)) * 8;
        gsrc[i] = Wh1T + ((size_t)(h * 64 + row_l)) * 4096 + sc;
    }
    u16* ldst = &whT[wv * 2048];              // + i*512 per inst (wave-uniform)
    const int xb7 = l15 & 7;                  // read-side swizzle key

    f32x4 accd[2], accz;
    #pragma unroll
    for (int j = 0; j < 2; ++j)
        #pragma unroll
        for (int r = 0; r < 4; ++r) accd[j][r] = 0.f;
    #pragma unroll
    for (int r = 0; r < 4; ++r) accz[r] = 0.f;

    // initial prefetch: iter-0 adj tile (4 rows/thread) + F2 vector
    int4 aprev[4];
    #pragma unroll
    for (int i = 0; i < 4; ++i)
        aprev[i] = *(const int4*)&adj1[(size_t)(n0 + rg + 8 * i) * N + c4];
    float4 f2n = *(const float4*)&F2[h * N + c4];
    __syncthreads();

    for (int m0 = 0; m0 < 4096; m0 += 128) {
        // ---- issue whT DMA for this tile (covered by mask-gen VALU) ----
        #pragma unroll
        for (int i = 0; i < 4; ++i)
            gload_lds16(gsrc[i] + m0, ldst + i * 512);
        // ---- mask-gen; consume aprev[i], immediately issue its replacement ----
        const float4 F2v = f2n;
        const int mn = (m0 + 128 < 4096) ? m0 + 128 : 0;   // wrap harmless
        f2n = *(const float4*)&F2[h * N + mn + c4];
        #pragma unroll
        for (int i = 0; i < 4; ++i) {
            const int rr = rg + 8 * i;
            int4 a4 = aprev[i];
            aprev[i] = *(const int4*)&adj1[(size_t)(n0 + rr) * N + mn + c4];
            float f1v = f1s[rr];
            float w0 = mexp(a4.x, f1v + F2v.x);
            float w1 = mexp(a4.y, f1v + F2v.y);
            float w2 = mexp(a4.z, f1v + F2v.z);
            float w3 = mexp(a4.w, f1v + F2v.w);
            uint2 pk;
            pk.x = pk2(w0, w1);
            pk.y = pk2(w2, w3);
            *(uint2*)&wbf[rr * 136 + c4] = pk;
        }
        __syncthreads();   // vmcnt(0) drain: DMA + prefetches already covered
        // ---- compute: 4 K-steps x (2 data frags + ones frag on dh==0) ----
        #pragma unroll
        for (int ks = 0; ks < 4; ++ks) {
            int k0 = ks * 32 + q * 8;
            bf16x8 a = *(const bf16x8*)&wbf[(rb + l15) * 136 + k0];
            #pragma unroll
            for (int j = 0; j < 2; ++j) {
                const int df = dh * 2 + j;
                bf16x8 b = *(const bf16x8*)
                    &whT[(df * 16 + l15) * 128 + (((ks * 4 + q) ^ xb7) * 8)];
                accd[j] = __builtin_amdgcn_mfma_f32_16x16x32_bf16(a, b, accd[j], 0, 0, 0);
            }
            if (dh == 0)
                accz = __builtin_amdgcn_mfma_f32_16x16x32_bf16(a, bones, accz, 0, 0, 0);
        }
        __syncthreads();
    }
    // denominator broadcast across the df-split, then normalize + ELU -> h1
    if (dh == 0 && l15 == 0) {
        #pragma unroll
        for (int r = 0; r < 4; ++r) zs[rb + q * 4 + r] = accz[r];
    }
    __syncthreads();
    #pragma unroll
    for (int r = 0; r < 4; ++r) {
        const int nl = rb + q * 4 + r;
        const float z = fmaxf(zs[nl], 1e-30f);
        #pragma unroll
        for (int j = 0; j < 2; ++j) {
            float v = accd[j][r] / z;
            v = v > 0.f ? v : __expf(v) - 1.f;
            h1[(size_t)(n0 + nl) * 512 + h * 64 + (dh * 2 + j) * 16 + l15] = v;
        }
    }
}

// ---------------- K4: fused Wh2 GEMM + F1o/F2o + Wh2T bf16 ----------------------
// wave = one n (lane = c); grid 1024 x 256.
__global__ __launch_bounds__(256) void k4_gemm2(const float* __restrict__ h1,
                                                const float* __restrict__ Wo,
                                                const float* __restrict__ ao,
                                                float* __restrict__ F1o,
                                                float* __restrict__ F2o,
                                                u16* __restrict__ Wh2T) {
    const int t = threadIdx.x;
    const int c = t & 63;
    const int n = blockIdx.x * 4 + (t >> 6);
    float acc = 0.f;
    if (c < NCLASS) {
        const float* hrow = &h1[(size_t)n * 512];
        #pragma unroll 8
        for (int f = 0; f < 512; ++f)
            acc += hrow[f] * Wo[f * NCLASS + c];
        Wh2T[(size_t)c * 4096 + n] = f2b(acc);
    }
    float s1 = (c < NCLASS) ? acc * ao[c] : 0.f;
    float s2 = (c < NCLASS) ? acc * ao[NCLASS + c] : 0.f;
    #pragma unroll
    for (int off = 32; off >= 1; off >>= 1) {
        s1 += __shfl_xor(s1, off);
        s2 += __shfl_xor(s2, off);
    }
    if (c == 0) {
        F1o[n] = s1 * LOG2E;
        F2o[n] = s2 * LOG2E;
    }
}

// ---------------- K5a: layer-2 attention, k3-r7 skeleton transplant -------------
// Round-14 proven version: 32-row n-tiles x 8 m-chunks (512 cols, 4 iters).
// LDS 21.2 KB -> 4 blocks/CU at grid (128, 8) = 1024 blocks.
__global__ __launch_bounds__(256, 4) void k5a_attn2(const int* __restrict__ adj0,
                                                    const u16* __restrict__ Wh2T,
                                                    const float* __restrict__ F1o,
                                                    const float* __restrict__ F2o,
                                                    float* __restrict__ pacc,
                                                    float* __restrict__ pz) {
    __shared__ __align__(16) u16 wbf[32 * 136];   // A-tile, pitch 136
    __shared__ __align__(16) u16 whT[48 * 128];   // rows 0..39 data, 40..47 zero
    __shared__ float f1s[32];
    const int t     = threadIdx.x;
    const int n0    = blockIdx.x * 32;
    const int chunk = blockIdx.y;                 // 0..7
    const int mbase = chunk * 512;
    const int lane  = t & 63;
    const int l15   = lane & 15;
    const int q     = lane >> 4;
    const int wv    = t >> 6;
    const int rb    = (wv & 1) * 16;              // row-block base
    const int dh    = wv >> 1;                    // 0: df0+ones, 1: df1+df2
    const int c4    = (t & 31) * 4;
    const int rg    = t >> 5;                     // mask-gen row group 0..7
    const bf16x8 bones = ones_frag();
    if (t < 32) f1s[t] = F1o[n0 + t];
    // zero pad rows 40..47 (read by df=2 frag, lanes l15>=8); 8*128 = 1024
    #pragma unroll
    for (int i = 0; i < 4; ++i)
        whT[40 * 128 + t + 256 * i] = 0;

    // gl_lds staging: wave 0 rows 0..15 (4 insts), wave 1 rows 16..31 (4),
    // wave 2 rows 32..39 (2), wave 3 none. Source pre-swizzled.
    const int lsub = lane >> 4;
    const int slot = lane & 15;
    const int ninst = (wv < 2) ? 4 : ((wv == 2) ? 2 : 0);
    const u16* gsrc[4];
    #pragma unroll
    for (int i = 0; i < 4; ++i) {
        int row_l = wv * 16 + i * 4 + lsub;
        int rl    = (row_l < 40) ? row_l : 0;     // keep addr in-bounds for unused insts
        int sc    = (slot ^ ((i * 4 + lsub) & 7)) * 8;
        gsrc[i] = Wh2T + (size_t)rl * 4096 + sc;
    }
    u16* ldst = &whT[wv * 2048];
    const int xb7 = l15 & 7;

    f32x4 acc0, acc1, accz;
    #pragma unroll
    for (int r = 0; r < 4; ++r) { acc0[r] = 0.f; acc1[r] = 0.f; accz[r] = 0.f; }

    // initial prefetch: iter-0 adj tile (4 rows/thread) + F2 vector
    int4 aprev[4];
    #pragma unroll
    for (int i = 0; i < 4; ++i)
        aprev[i] = *(const int4*)&adj0[(size_t)(n0 + rg + 8 * i) * N + mbase + c4];
    float4 f2n = *(const float4*)&F2o[mbase + c4];
    __syncthreads();

    for (int it = 0; it < 4; ++it) {
        const int m0 = mbase + it * 128;
        // ---- issue whT DMA for this tile (covered by mask-gen VALU) ----
        #pragma unroll
        for (int i = 0; i < 4; ++i)
            if (i < ninst)
                gload_lds16(gsrc[i] + m0, ldst + i * 512);
        // ---- mask-gen; consume aprev[i], immediately issue its replacement ----
        const float4 F2v = f2n;
        const int mn = (it < 3) ? m0 + 128 : mbase;   // wrap harmless
        f2n = *(const float4*)&F2o[mn + c4];
        #pragma unroll
        for (int i = 0; i < 4; ++i) {
            const int rr = rg + 8 * i;
            int4 a4 = aprev[i];
            aprev[i] = *(const int4*)&adj0[(size_t)(n0 + rr) * N + mn + c4];
            float f1v = f1s[rr];
            float w0 = mexp(a4.x, f1v + F2v.x);
            float w1 = mexp(a4.y, f1v + F2v.y);
            float w2 = mexp(a4.z, f1v + F2v.z);
            float w3 = mexp(a4.w, f1v + F2v.w);
            uint2 pk;
            pk.x = pk2(w0, w1);
            pk.y = pk2(w2, w3);
            *(uint2*)&wbf[rr * 136 + c4] = pk;
        }
        __syncthreads();   // vmcnt(0) drain: DMA + prefetches already covered
        // ---- compute: 4 K-steps x 2 MFMAs per wave (wave-uniform dh split) ----
        #pragma unroll
        for (int ks = 0; ks < 4; ++ks) {
            int k0 = ks * 32 + q * 8;
            bf16x8 a = *(const bf16x8*)&wbf[(rb + l15) * 136 + k0];
            const int sl = (((ks * 4 + q) ^ xb7) * 8);
            if (dh == 0) {
                bf16x8 b0 = *(const bf16x8*)&whT[(0 * 16 + l15) * 128 + sl];
                acc0 = __builtin_amdgcn_mfma_f32_16x16x32_bf16(a, b0, acc0, 0, 0, 0);
                accz = __builtin_amdgcn_mfma_f32_16x16x32_bf16(a, bones, accz, 0, 0, 0);
            } else {
                bf16x8 b1 = *(const bf16x8*)&whT[(1 * 16 + l15) * 128 + sl];
                acc0 = __builtin_amdgcn_mfma_f32_16x16x32_bf16(a, b1, acc0, 0, 0, 0);
                bf16x8 b2 = *(const bf16x8*)&whT[(2 * 16 + l15) * 128 + sl];
                acc1 = __builtin_amdgcn_mfma_f32_16x16x32_bf16(a, b2, acc1, 0, 0, 0);
            }
        }
        __syncthreads();
    }
    // write partials: dh=0 -> cols 0..15 + pz; dh=1 -> cols 16..39
    #pragma unroll
    for (int r = 0; r < 4; ++r) {
        const int n = n0 + rb + q * 4 + r;
        const size_t base = ((size_t)chunk * N + n) * NCLASS;
        if (dh == 0) {
            if (l15 == 0) pz[(size_t)chunk * N + n] = accz[r];
            pacc[base + l15] = acc0[r];
        } else {
            pacc[base + 16 + l15] = acc0[r];
            if (l15 < 8) pacc[base + 32 + l15] = acc1[r];
        }
    }
}

// ---------------- K5b: reduce 8 chunks, ELU, log_softmax, f32 store -------------
__global__ __launch_bounds__(256) void k5b_final(const float* __restrict__ pacc,
                                                 const float* __restrict__ pz,
                                                 float* __restrict__ out) {
    const int t = threadIdx.x;
    const int lane = t & 63;
    const int n = blockIdx.x * 4 + (t >> 6);
    float s = 0.f, Z = 0.f;
    #pragma unroll
    for (int ch = 0; ch < 8; ++ch) {
        Z += pz[(size_t)ch * N + n];
        if (lane < NCLASS) s += pacc[(size_t)(ch * N + n) * NCLASS + lane];
    }
    float v;
    if (lane < NCLASS) {
        v = s / fmaxf(Z, 1e-30f);
        v = v > 0.f ? v : __expf(v) - 1.f;
    } else {
        v = -INFINITY;
    }
    float mx = v;
    #pragma unroll
    for (int off = 32; off >= 1; off >>= 1) mx = fmaxf(mx, __shfl_xor(mx, off));
    float ex = (lane < NCLASS) ? __expf(v - mx) : 0.f;
    #pragma unroll
    for (int off = 32; off >= 1; off >>= 1) ex += __shfl_xor(ex, off);
    float lse = mx + __logf(ex);
    if (lane < NCLASS) out[(size_t)n * NCLASS + lane] = v - lse;
}

// ---------------------------------------------------------------------------------
extern "C" void kernel_launch(void* const* d_in, const int* in_sizes, int n_in,
                              void* d_out, int out_size, void* d_ws, size_t ws_size,
                              hipStream_t stream) {
    const float* x   = (const float*)d_in[0];
    const int*   adj = (const int*)d_in[1];
    const float* W1  = (const float*)d_in[2];
    const float* a1  = (const float*)d_in[3];
    const float* Wo  = (const float*)d_in[4];
    const float* ao  = (const float*)d_in[5];

    float* ws    = (float*)d_ws;
    float* h1    = ws;                        // 2,097,152
    float* F1    = h1 + 2097152;              // 32,768
    float* F2    = F1 + 32768;                // 32,768
    float* F1o   = F2 + 32768;                // 4,096
    float* F2o   = F1o + 4096;                // 4,096
    float* pz    = F2o + 4096;                // 32,768 (8*4096, k5a)
    float* pz1   = pz + 65536;                // 65,536 (unused)
    u16*   Wh1T  = (u16*)(pz1 + 65536);       // 2,097,152 u16
    u16*   Wh2T  = Wh1T + 2097152;            // 163,840 u16
    float* R     = (float*)(Wh2T + 163840);   // 4,194,304 f32 shared region
    u16*   xb    = (u16*)R;                   // kcx -> k1m (dies before k3)
    u16*   W1b   = xb + 2097152;              // kcw -> k1m (dies before k3)
    float* pacc  = R;                         // k5a -> k5b (8*4096*40)

    const int* adj0 = adj;                    // layer-2 mask
    const int* adj1 = adj + (size_t)N * N;    // layer-1 mask

    hipLaunchKernelGGL(kcx,       dim3(1024),   dim3(256), 0, stream, x, xb);
    hipLaunchKernelGGL(kcw,       dim3(8, 8),   dim3(256), 0, stream, W1, W1b);
    hipLaunchKernelGGL(k1m_gemm1, dim3(128, 8), dim3(256), 0, stream, xb, W1b, a1, Wh1T, F1, F2);
    hipLaunchKernelGGL(k3_attn1,  dim3(128, 8), dim3(256), 0, stream, adj1, Wh1T, F1, F2, h1);
    hipLaunchKernelGGL(k4_gemm2,  dim3(1024),   dim3(256), 0, stream, h1, Wo, ao, F1o, F2o, Wh2T);
    hipLaunchKernelGGL(k5a_attn2, dim3(128, 8), dim3(256), 0, stream, adj0, Wh2T, F1o, F2o, pacc, pz);
    hipLaunchKernelGGL(k5b_final, dim3(1024),   dim3(256), 0, stream, pacc, pz, (float*)d_out);
}

// Round 17
// 298.890 us; speedup vs baseline: 1.0944x; 1.0044x over previous
//
#include <hip/hip_runtime.h>
#include <hip/hip_bf16.h>

#define N      4096
#define NFEAT  512
#define NHID   64
#define NHEADS 8
#define NCLASS 40
#define ALPHA  0.2f
#define LOG2E  1.44269504f

typedef unsigned short u16;
typedef unsigned int   u32;
typedef __attribute__((ext_vector_type(8))) short bf16x8;
typedef __attribute__((ext_vector_type(4))) float f32x4;

// bf16 bits -> f32
__device__ __forceinline__ float b2f(u16 u) {
    return __uint_as_float(((u32)u) << 16);
}
// RNE-rounded value kept in HIGH 16 bits
__device__ __forceinline__ u32 rnd_hi(float f) {
    u32 u = __float_as_uint(f);
    return u + 0x7FFFu + ((u >> 16) & 1u);
}
// pack two f32 -> two bf16 (lo in low 16) via HW v_cvt_pk_bf16_f32 (gfx950)
__device__ __forceinline__ u32 pk2(float lo, float hi) {
    __hip_bfloat162 h = __float22bfloat162_rn(make_float2(lo, hi));
    return *(u32*)&h;
}
// single f32 -> bf16 bits (RNE)
__device__ __forceinline__ u16 f2b(float f) {
    return (u16)(rnd_hi(f) >> 16);
}
// masked exp2 of leaky-relu in log2 domain: raw v_exp_f32, no OCML guards
__device__ __forceinline__ float mexp(int m, float t) {
    return m ? __builtin_amdgcn_exp2f(fmaxf(t, ALPHA * t)) : 0.f;
}
// constant all-ones bf16 B-fragment (every output column = row sum)
__device__ __forceinline__ bf16x8 ones_frag() {
    union { u16 u[8]; bf16x8 v; } o;
    #pragma unroll
    for (int j = 0; j < 8; ++j) o.u[j] = 0x3F80;
    return o.v;
}
// async global->LDS DMA, 16B per lane; LDS dest = wave-uniform base + lane*16.
// Completion is guaranteed by the vmcnt(0) drain inside __syncthreads().
__device__ __forceinline__ void gload_lds16(const u16* g, u16* l) {
    __builtin_amdgcn_global_load_lds(
        (const __attribute__((address_space(1))) void*)g,
        (__attribute__((address_space(3))) void*)l,
        16, 0, 0);
}

// ---------------- KPREP: kcx + kcw merged (independent, run concurrently) -------
// blocks 0..1023: x f32 -> xb bf16. blocks 1024..1087: W1 [h][f][d] -> W1b [h][d][f].
__global__ __launch_bounds__(256) void kprep(const float* __restrict__ x,
                                             u16* __restrict__ xb,
                                             const float* __restrict__ W1,
                                             u16* __restrict__ W1b) {
    __shared__ float ts[64 * 68];   // kcw transpose tile, pitch 68
    const int t = threadIdx.x;
    if (blockIdx.x < 1024) {
        // ---- kcx body ----
        const int g = blockIdx.x * 256 + t;             // 262144 threads x 8 elems
        const size_t base = (size_t)g * 8;
        float4 v0 = *(const float4*)&x[base];
        float4 v1 = *(const float4*)&x[base + 4];
        uint4 o;
        o.x = pk2(v0.x, v0.y); o.y = pk2(v0.z, v0.w);
        o.z = pk2(v1.x, v1.y); o.w = pk2(v1.z, v1.w);
        *(uint4*)&xb[base] = o;
        return;
    }
    // ---- kcw body ----
    const int bx = blockIdx.x - 1024;                   // 0..63
    const int f0 = (bx & 7) * 64;
    const int h  = bx >> 3;
    #pragma unroll
    for (int i = 0; i < 4; ++i) {
        int flat = t + 256 * i;
        int row = flat >> 4;                    // f-local
        int c4  = (flat & 15) * 4;              // d
        *(float4*)&ts[row * 68 + c4] =
            *(const float4*)&W1[((size_t)h * 512 + f0 + row) * 64 + c4];
    }
    __syncthreads();
    const int d  = t >> 2;
    const int fs = (t & 3) * 16;
    u32 p[8];
    #pragma unroll
    for (int j = 0; j < 8; ++j)
        p[j] = pk2(ts[(fs + 2 * j) * 68 + d], ts[(fs + 2 * j + 1) * 68 + d]);
    u32* dst = (u32*)&W1b[((size_t)(h * 64 + d)) * 512 + f0 + fs];
    *(uint4*)dst       = make_uint4(p[0], p[1], p[2], p[3]);
    *(uint4*)(dst + 4) = make_uint4(p[4], p[5], p[6], p[7]);
}

// ---------------- K1M: Wh1T bf16 + fused F1/F2 epilogue, 32-row tiles -----------
// Round-15 proven version: 32-row n-tiles, grid (128, 8) = 4 blocks/CU, wave
// split rb/dh, gl_lds dbuf + XOR swizzle, 2-partial F1/F2 LDS combine.
__global__ __launch_bounds__(256, 4) void k1m_gemm1(const u16* __restrict__ xb,
                                                    const u16* __restrict__ W1b,
                                                    const float* __restrict__ a1,
                                                    u16* __restrict__ Wh1T,
                                                    float* __restrict__ F1,
                                                    float* __restrict__ F2) {
    __shared__ __align__(16) u16 xs[2][32 * 64];    // [n-local][f-chunk]
    __shared__ __align__(16) u16 wvs[2][64 * 64];   // [d][f-chunk]
    __shared__ float fp[2][2][32];                  // [s1|s2][dh][row]
    const int t    = threadIdx.x;
    const int n0   = blockIdx.x * 32;
    const int h    = blockIdx.y;
    const int lane = t & 63;
    const int l15  = lane & 15;
    const int q    = lane >> 4;
    const int wv   = t >> 6;
    const int rb   = (wv & 1) * 16;    // row-block base
    const int dh   = wv >> 1;          // df-half: df = dh*2+j
    const int lsub = lane >> 3;        // row-sub 0..7
    const int slot = lane & 7;         // 16B col slot 0..7
    const int xb7  = l15 & 7;          // read-side swizzle key

    // DMA sources, pre-swizzled: LDS[r][slot] = G[r][slot ^ (r&7)]; r&7 == lsub
    // xs: wave wv stages rows wv*8..+7 (1 inst); wvs: rows wv*16..+15 (2 insts)
    const u16* gx = xb + (size_t)(n0 + wv * 8 + lsub) * 512 + (slot ^ lsub) * 8;
    const u16* gw[2];
    #pragma unroll
    for (int i = 0; i < 2; ++i)
        gw[i] = W1b + ((size_t)(h * 64 + wv * 16 + i * 8 + lsub)) * 512
                    + (slot ^ lsub) * 8;

    f32x4 acc[2];
    #pragma unroll
    for (int j = 0; j < 2; ++j)
        #pragma unroll
        for (int r = 0; r < 4; ++r) acc[j][r] = 0.f;

#define K1_DMA(P, F0)                                                          \
    {                                                                          \
        gload_lds16(gx + (F0), &xs[P][(wv * 8) * 64]);                         \
        _Pragma("unroll")                                                      \
        for (int i = 0; i < 2; ++i)                                            \
            gload_lds16(gw[i] + (F0), &wvs[P][(wv * 16 + i * 8) * 64]);        \
    }
#define K1_MFMA(P)                                                            \
    {                                                                          \
        _Pragma("unroll")                                                      \
        for (int ks = 0; ks < 2; ++ks) {                                       \
            const int sl = ((ks * 4 + q) ^ xb7) * 8;                           \
            bf16x8 a = *(const bf16x8*)&xs[P][(rb + l15) * 64 + sl];           \
            _Pragma("unroll")                                                  \
            for (int j = 0; j < 2; ++j) {                                      \
                bf16x8 b = *(const bf16x8*)                                    \
                    &wvs[P][((dh * 2 + j) * 16 + l15) * 64 + sl];              \
                acc[j] = __builtin_amdgcn_mfma_f32_16x16x32_bf16(a, b, acc[j], 0, 0, 0); \
            }                                                                  \
        }                                                                      \
    }

    K1_DMA(0, 0)
    __syncthreads();
    for (int f0 = 0; f0 < 512; f0 += 128) {
        K1_DMA(1, f0 + 64)          // covered by MFMA(0) + other waves
        K1_MFMA(0)
        __syncthreads();            // drains DMA -> buf1 ready
        if (f0 + 128 < 512)
            K1_DMA(0, f0 + 128)
        K1_MFMA(1)
        __syncthreads();
    }
#undef K1_DMA
#undef K1_MFMA

    // Wh1T store: C row = q*4+r (n-local), col = l15 (d-local), df = dh*2+j
    #pragma unroll
    for (int j = 0; j < 2; ++j) {
        uint2 o;
        o.x = pk2(acc[j][0], acc[j][1]);
        o.y = pk2(acc[j][2], acc[j][3]);
        *(uint2*)&Wh1T[((size_t)(h * 64 + (dh * 2 + j) * 16 + l15)) * 4096
                       + n0 + rb + q * 4] = o;
    }
    // fused F1/F2: per-dh partial over its 2 dfs, shfl-reduce over l15,
    // then cross-wave combine via LDS.
    float a1v[2], a2v[2];
    #pragma unroll
    for (int j = 0; j < 2; ++j) {
        a1v[j] = a1[h * 128 + (dh * 2 + j) * 16 + l15];
        a2v[j] = a1[h * 128 + 64 + (dh * 2 + j) * 16 + l15];
    }
    #pragma unroll
    for (int r = 0; r < 4; ++r) {
        float s1 = 0.f, s2 = 0.f;
        #pragma unroll
        for (int j = 0; j < 2; ++j) {
            s1 += acc[j][r] * a1v[j];
            s2 += acc[j][r] * a2v[j];
        }
        #pragma unroll
        for (int off = 8; off >= 1; off >>= 1) {
            s1 += __shfl_xor(s1, off);
            s2 += __shfl_xor(s2, off);
        }
        if (l15 == 0) {
            fp[0][dh][rb + q * 4 + r] = s1;
            fp[1][dh][rb + q * 4 + r] = s2;
        }
    }
    __syncthreads();
    if (t < 32) {
        F1[h * 4096 + n0 + t] = (fp[0][0][t] + fp[0][1][t]) * LOG2E;
        F2[h * 4096 + n0 + t] = (fp[1][0][t] + fp[1][1][t]) * LOG2E;
    }
}

// ---------------- K3: layer-1 attention, fused, 32-row tiles --------------------
// Round-7 proven version (measured 78 us; declared structural floor after the
// r8-r13 matrix: VALU-cut, conflict-cut, occupancy up/down, barrier-halving,
// counted-vmcnt all null-to-negative). LDS 24.8 KB -> 4 blocks/CU.
// grid (128 n-tiles, 8 heads) x 256.
__global__ __launch_bounds__(256, 4) void k3_attn1(const int* __restrict__ adj1,
                                                   const u16* __restrict__ Wh1T,
                                                   const float* __restrict__ F1,
                                                   const float* __restrict__ F2,
                                                   float* __restrict__ h1) {
    __shared__ __align__(16) u16 wbf[32 * 136];   // A-tile, pitch 136
    __shared__ __align__(16) u16 whT[64 * 128];   // B-tile, linear+swizzled
    __shared__ float f1s[32];
    __shared__ float zs[32];
    const int t     = threadIdx.x;
    const int n0    = blockIdx.x * 32;
    const int h     = blockIdx.y;
    const int lane  = t & 63;
    const int l15   = lane & 15;
    const int q     = lane >> 4;
    const int wv    = t >> 6;
    const int rb    = (wv & 1) * 16;          // row-block base
    const int dh    = wv >> 1;                // df-half: computes df = dh*2+j
    const int c4    = (t & 31) * 4;           // mask-gen: 4 consecutive cols
    const int rg    = t >> 5;                 // mask-gen: row group 0..7
    const bf16x8 bones = ones_frag();
    if (t < 32) f1s[t] = F1[h * N + n0 + t];

    // gl_lds staging map (whT = head's full 64 d-rows): wave wv, inst i covers
    // rows wv*16+i*4 .. +3; source pre-swizzled slot j = slot^(row&7)
    const int lsub = lane >> 4;
    const int slot = lane & 15;
    const u16* gsrc[4];
    #pragma unroll
    for (int i = 0; i < 4; ++i) {
        int row_l = wv * 16 + i * 4 + lsub;
        int sc    = (slot ^ ((i * 4 + lsub) & 7)) * 8;
        gsrc[i] = Wh1T + ((size_t)(h * 64 + row_l)) * 4096 + sc;
    }
    u16* ldst = &whT[wv * 2048];              // + i*512 per inst (wave-uniform)
    const int xb7 = l15 & 7;                  // read-side swizzle key

    f32x4 accd[2], accz;
    #pragma unroll
    for (int j = 0; j < 2; ++j)
        #pragma unroll
        for (int r = 0; r < 4; ++r) accd[j][r] = 0.f;
    #pragma unroll
    for (int r = 0; r < 4; ++r) accz[r] = 0.f;

    // initial prefetch: iter-0 adj tile (4 rows/thread) + F2 vector
    int4 aprev[4];
    #pragma unroll
    for (int i = 0; i < 4; ++i)
        aprev[i] = *(const int4*)&adj1[(size_t)(n0 + rg + 8 * i) * N + c4];
    float4 f2n = *(const float4*)&F2[h * N + c4];
    __syncthreads();

    for (int m0 = 0; m0 < 4096; m0 += 128) {
        // ---- issue whT DMA for this tile (covered by mask-gen VALU) ----
        #pragma unroll
        for (int i = 0; i < 4; ++i)
            gload_lds16(gsrc[i] + m0, ldst + i * 512);
        // ---- mask-gen; consume aprev[i], immediately issue its replacement ----
        const float4 F2v = f2n;
        const int mn = (m0 + 128 < 4096) ? m0 + 128 : 0;   // wrap harmless
        f2n = *(const float4*)&F2[h * N + mn + c4];
        #pragma unroll
        for (int i = 0; i < 4; ++i) {
            const int rr = rg + 8 * i;
            int4 a4 = aprev[i];
            aprev[i] = *(const int4*)&adj1[(size_t)(n0 + rr) * N + mn + c4];
            float f1v = f1s[rr];
            float w0 = mexp(a4.x, f1v + F2v.x);
            float w1 = mexp(a4.y, f1v + F2v.y);
            float w2 = mexp(a4.z, f1v + F2v.z);
            float w3 = mexp(a4.w, f1v + F2v.w);
            uint2 pk;
            pk.x = pk2(w0, w1);
            pk.y = pk2(w2, w3);
            *(uint2*)&wbf[rr * 136 + c4] = pk;
        }
        __syncthreads();   // vmcnt(0) drain: DMA + prefetches already covered
        // ---- compute: 4 K-steps x (2 data frags + ones frag on dh==0) ----
        #pragma unroll
        for (int ks = 0; ks < 4; ++ks) {
            int k0 = ks * 32 + q * 8;
            bf16x8 a = *(const bf16x8*)&wbf[(rb + l15) * 136 + k0];
            #pragma unroll
            for (int j = 0; j < 2; ++j) {
                const int df = dh * 2 + j;
                bf16x8 b = *(const bf16x8*)
                    &whT[(df * 16 + l15) * 128 + (((ks * 4 + q) ^ xb7) * 8)];
                accd[j] = __builtin_amdgcn_mfma_f32_16x16x32_bf16(a, b, accd[j], 0, 0, 0);
            }
            if (dh == 0)
                accz = __builtin_amdgcn_mfma_f32_16x16x32_bf16(a, bones, accz, 0, 0, 0);
        }
        __syncthreads();
    }
    // denominator broadcast across the df-split, then normalize + ELU -> h1
    if (dh == 0 && l15 == 0) {
        #pragma unroll
        for (int r = 0; r < 4; ++r) zs[rb + q * 4 + r] = accz[r];
    }
    __syncthreads();
    #pragma unroll
    for (int r = 0; r < 4; ++r) {
        const int nl = rb + q * 4 + r;
        const float z = fmaxf(zs[nl], 1e-30f);
        #pragma unroll
        for (int j = 0; j < 2; ++j) {
            float v = accd[j][r] / z;
            v = v > 0.f ? v : __expf(v) - 1.f;
            h1[(size_t)(n0 + nl) * 512 + h * 64 + (dh * 2 + j) * 16 + l15] = v;
        }
    }
}

// ---------------- K4: fused Wh2 GEMM + F1o/F2o + Wh2T bf16, 2-wave f-split ------
// 2 waves per n (f 0..255 / 256..511) halve the serial FMA chain; partials
// combined via LDS. grid 2048 x 256 (2 n per block).
__global__ __launch_bounds__(256) void k4_gemm2(const float* __restrict__ h1,
                                                const float* __restrict__ Wo,
                                                const float* __restrict__ ao,
                                                float* __restrict__ F1o,
                                                float* __restrict__ F2o,
                                                u16* __restrict__ Wh2T) {
    __shared__ float part[2][2][64];   // [n-local][f-half][lane]
    const int t  = threadIdx.x;
    const int c  = t & 63;
    const int w  = (t >> 6) & 1;       // f-half
    const int nn = t >> 7;             // n-local 0..1
    const int n  = blockIdx.x * 2 + nn;
    float acc = 0.f;
    if (c < NCLASS) {
        const float* hrow = &h1[(size_t)n * 512 + w * 256];
        const float* wcol = &Wo[(size_t)(w * 256) * NCLASS + c];
        #pragma unroll 8
        for (int f = 0; f < 256; ++f)
            acc += hrow[f] * wcol[f * NCLASS];
    }
    part[nn][w][c] = acc;
    __syncthreads();
    if (w == 0) {
        float tot = part[nn][0][c] + part[nn][1][c];
        if (c < NCLASS)
            Wh2T[(size_t)c * 4096 + n] = f2b(tot);
        float s1 = (c < NCLASS) ? tot * ao[c] : 0.f;
        float s2 = (c < NCLASS) ? tot * ao[NCLASS + c] : 0.f;
        #pragma unroll
        for (int off = 32; off >= 1; off >>= 1) {
            s1 += __shfl_xor(s1, off);
            s2 += __shfl_xor(s2, off);
        }
        if (c == 0) {
            F1o[n] = s1 * LOG2E;
            F2o[n] = s2 * LOG2E;
        }
    }
}

// ---------------- K5a: layer-2 attention, k3-r7 skeleton transplant -------------
// Round-14 proven version: 32-row n-tiles x 8 m-chunks (512 cols, 4 iters).
// LDS 21.2 KB -> 4 blocks/CU at grid (128, 8) = 1024 blocks.
__global__ __launch_bounds__(256, 4) void k5a_attn2(const int* __restrict__ adj0,
                                                    const u16* __restrict__ Wh2T,
                                                    const float* __restrict__ F1o,
                                                    const float* __restrict__ F2o,
                                                    float* __restrict__ pacc,
                                                    float* __restrict__ pz) {
    __shared__ __align__(16) u16 wbf[32 * 136];   // A-tile, pitch 136
    __shared__ __align__(16) u16 whT[48 * 128];   // rows 0..39 data, 40..47 zero
    __shared__ float f1s[32];
    const int t     = threadIdx.x;
    const int n0    = blockIdx.x * 32;
    const int chunk = blockIdx.y;                 // 0..7
    const int mbase = chunk * 512;
    const int lane  = t & 63;
    const int l15   = lane & 15;
    const int q     = lane >> 4;
    const int wv    = t >> 6;
    const int rb    = (wv & 1) * 16;              // row-block base
    const int dh    = wv >> 1;                    // 0: df0+ones, 1: df1+df2
    const int c4    = (t & 31) * 4;
    const int rg    = t >> 5;                     // mask-gen row group 0..7
    const bf16x8 bones = ones_frag();
    if (t < 32) f1s[t] = F1o[n0 + t];
    // zero pad rows 40..47 (read by df=2 frag, lanes l15>=8); 8*128 = 1024
    #pragma unroll
    for (int i = 0; i < 4; ++i)
        whT[40 * 128 + t + 256 * i] = 0;

    // gl_lds staging: wave 0 rows 0..15 (4 insts), wave 1 rows 16..31 (4),
    // wave 2 rows 32..39 (2), wave 3 none. Source pre-swizzled.
    const int lsub = lane >> 4;
    const int slot = lane & 15;
    const int ninst = (wv < 2) ? 4 : ((wv == 2) ? 2 : 0);
    const u16* gsrc[4];
    #pragma unroll
    for (int i = 0; i < 4; ++i) {
        int row_l = wv * 16 + i * 4 + lsub;
        int rl    = (row_l < 40) ? row_l : 0;     // keep addr in-bounds for unused insts
        int sc    = (slot ^ ((i * 4 + lsub) & 7)) * 8;
        gsrc[i] = Wh2T + (size_t)rl * 4096 + sc;
    }
    u16* ldst = &whT[wv * 2048];
    const int xb7 = l15 & 7;

    f32x4 acc0, acc1, accz;
    #pragma unroll
    for (int r = 0; r < 4; ++r) { acc0[r] = 0.f; acc1[r] = 0.f; accz[r] = 0.f; }

    // initial prefetch: iter-0 adj tile (4 rows/thread) + F2 vector
    int4 aprev[4];
    #pragma unroll
    for (int i = 0; i < 4; ++i)
        aprev[i] = *(const int4*)&adj0[(size_t)(n0 + rg + 8 * i) * N + mbase + c4];
    float4 f2n = *(const float4*)&F2o[mbase + c4];
    __syncthreads();

    for (int it = 0; it < 4; ++it) {
        const int m0 = mbase + it * 128;
        // ---- issue whT DMA for this tile (covered by mask-gen VALU) ----
        #pragma unroll
        for (int i = 0; i < 4; ++i)
            if (i < ninst)
                gload_lds16(gsrc[i] + m0, ldst + i * 512);
        // ---- mask-gen; consume aprev[i], immediately issue its replacement ----
        const float4 F2v = f2n;
        const int mn = (it < 3) ? m0 + 128 : mbase;   // wrap harmless
        f2n = *(const float4*)&F2o[mn + c4];
        #pragma unroll
        for (int i = 0; i < 4; ++i) {
            const int rr = rg + 8 * i;
            int4 a4 = aprev[i];
            aprev[i] = *(const int4*)&adj0[(size_t)(n0 + rr) * N + mn + c4];
            float f1v = f1s[rr];
            float w0 = mexp(a4.x, f1v + F2v.x);
            float w1 = mexp(a4.y, f1v + F2v.y);
            float w2 = mexp(a4.z, f1v + F2v.z);
            float w3 = mexp(a4.w, f1v + F2v.w);
            uint2 pk;
            pk.x = pk2(w0, w1);
            pk.y = pk2(w2, w3);
            *(uint2*)&wbf[rr * 136 + c4] = pk;
        }
        __syncthreads();   // vmcnt(0) drain: DMA + prefetches already covered
        // ---- compute: 4 K-steps x 2 MFMAs per wave (wave-uniform dh split) ----
        #pragma unroll
        for (int ks = 0; ks < 4; ++ks) {
            int k0 = ks * 32 + q * 8;
            bf16x8 a = *(const bf16x8*)&wbf[(rb + l15) * 136 + k0];
            const int sl = (((ks * 4 + q) ^ xb7) * 8);
            if (dh == 0) {
                bf16x8 b0 = *(const bf16x8*)&whT[(0 * 16 + l15) * 128 + sl];
                acc0 = __builtin_amdgcn_mfma_f32_16x16x32_bf16(a, b0, acc0, 0, 0, 0);
                accz = __builtin_amdgcn_mfma_f32_16x16x32_bf16(a, bones, accz, 0, 0, 0);
            } else {
                bf16x8 b1 = *(const bf16x8*)&whT[(1 * 16 + l15) * 128 + sl];
                acc0 = __builtin_amdgcn_mfma_f32_16x16x32_bf16(a, b1, acc0, 0, 0, 0);
                bf16x8 b2 = *(const bf16x8*)&whT[(2 * 16 + l15) * 128 + sl];
                acc1 = __builtin_amdgcn_mfma_f32_16x16x32_bf16(a, b2, acc1, 0, 0, 0);
            }
        }
        __syncthreads();
    }
    // write partials: dh=0 -> cols 0..15 + pz; dh=1 -> cols 16..39
    #pragma unroll
    for (int r = 0; r < 4; ++r) {
        const int n = n0 + rb + q * 4 + r;
        const size_t base = ((size_t)chunk * N + n) * NCLASS;
        if (dh == 0) {
            if (l15 == 0) pz[(size_t)chunk * N + n] = accz[r];
            pacc[base + l15] = acc0[r];
        } else {
            pacc[base + 16 + l15] = acc0[r];
            if (l15 < 8) pacc[base + 32 + l15] = acc1[r];
        }
    }
}

// ---------------- K5b: reduce 8 chunks, ELU, log_softmax, f32 store -------------
__global__ __launch_bounds__(256) void k5b_final(const float* __restrict__ pacc,
                                                 const float* __restrict__ pz,
                                                 float* __restrict__ out) {
    const int t = threadIdx.x;
    const int lane = t & 63;
    const int n = blockIdx.x * 4 + (t >> 6);
    float s = 0.f, Z = 0.f;
    #pragma unroll
    for (int ch = 0; ch < 8; ++ch) {
        Z += pz[(size_t)ch * N + n];
        if (lane < NCLASS) s += pacc[(size_t)(ch * N + n) * NCLASS + lane];
    }
    float v;
    if (lane < NCLASS) {
        v = s / fmaxf(Z, 1e-30f);
        v = v > 0.f ? v : __expf(v) - 1.f;
    } else {
        v = -INFINITY;
    }
    float mx = v;
    #pragma unroll
    for (int off = 32; off >= 1; off >>= 1) mx = fmaxf(mx, __shfl_xor(mx, off));
    float ex = (lane < NCLASS) ? __expf(v - mx) : 0.f;
    #pragma unroll
    for (int off = 32; off >= 1; off >>= 1) ex += __shfl_xor(ex, off);
    float lse = mx + __logf(ex);
    if (lane < NCLASS) out[(size_t)n * NCLASS + lane] = v - lse;
}

// ---------------------------------------------------------------------------------
extern "C" void kernel_launch(void* const* d_in, const int* in_sizes, int n_in,
                              void* d_out, int out_size, void* d_ws, size_t ws_size,
                              hipStream_t stream) {
    const float* x   = (const float*)d_in[0];
    const int*   adj = (const int*)d_in[1];
    const float* W1  = (const float*)d_in[2];
    const float* a1  = (const float*)d_in[3];
    const float* Wo  = (const float*)d_in[4];
    const float* ao  = (const float*)d_in[5];

    float* ws    = (float*)d_ws;
    float* h1    = ws;                        // 2,097,152
    float* F1    = h1 + 2097152;              // 32,768
    float* F2    = F1 + 32768;                // 32,768
    float* F1o   = F2 + 32768;                // 4,096
    float* F2o   = F1o + 4096;                // 4,096
    float* pz    = F2o + 4096;                // 32,768 (8*4096, k5a)
    float* pz1   = pz + 65536;                // 65,536 (unused)
    u16*   Wh1T  = (u16*)(pz1 + 65536);       // 2,097,152 u16
    u16*   Wh2T  = Wh1T + 2097152;            // 163,840 u16
    float* R     = (float*)(Wh2T + 163840);   // 4,194,304 f32 shared region
    u16*   xb    = (u16*)R;                   // kprep -> k1m (dies before k3)
    u16*   W1b   = xb + 2097152;              // kprep -> k1m (dies before k3)
    float* pacc  = R;                         // k5a -> k5b (8*4096*40)

    const int* adj0 = adj;                    // layer-2 mask
    const int* adj1 = adj + (size_t)N * N;    // layer-1 mask

    hipLaunchKernelGGL(kprep,     dim3(1088),   dim3(256), 0, stream, x, xb, W1, W1b);
    hipLaunchKernelGGL(k1m_gemm1, dim3(128, 8), dim3(256), 0, stream, xb, W1b, a1, Wh1T, F1, F2);
    hipLaunchKernelGGL(k3_attn1,  dim3(128, 8), dim3(256), 0, stream, adj1, Wh1T, F1, F2, h1);
    hipLaunchKernelGGL(k4_gemm2,  dim3(2048),   dim3(256), 0, stream, h1, Wo, ao, F1o, F2o, Wh2T);
    hipLaunchKernelGGL(k5a_attn2, dim3(128, 8), dim3(256), 0, stream, adj0, Wh2T, F1o, F2o, pacc, pz);
    hipLaunchKernelGGL(k5b_final, dim3(1024),   dim3(256), 0, stream, pacc, pz, (float*)d_out);
}